// Round 1
// baseline (1154.457 us; speedup 1.0000x reference)
//
#include <hip/hip_runtime.h>

// MVURE layer: 3x GATConv + view attention fusion.
// Workspace layout (needs ~137 MB):
//   feat   bf16 [3][N][128]   @ 0          (38,400,000 B)
//   el     f32  [3][N][8]     @ 38,400,000 ( 4,800,000 B)
//   er     f32  [3][N][8]     @ 43,200,000 ( 4,800,000 B)
//   views  f32  [3][N][128]   @ 48,000,000 (76,800,000 B)
//   offs   i32  [3][N+1]      @ 124,800,000 (600,012 B, padded to 600,016)
//   cursor i32  [3][N]        @ 125,400,016 (600,000 B)
//   esrc   i32  [3][E]        @ 126,000,016 (10,200,000 B)
//   counts i32  [3][N]        @ 136,200,016 (600,000 B)
//   scal   f32  logits[3],d[3],gc[6] @ 136,800,016 (48 B)

#define N_NODES 50000
#define DIM 128
#define OUTD 128
#define NH 8
#define NF 16
#define NE 850000            // 800000 random + 50000 self loops
#define NOFF 50001

typedef float f32x4 __attribute__((ext_vector_type(4)));
typedef __bf16 bf16x8 __attribute__((ext_vector_type(8)));

static __device__ __forceinline__ float bf2f(unsigned int u16) {
  return __uint_as_float(u16 << 16);
}
static __device__ __forceinline__ unsigned short f2bf(float f) {
  unsigned int u = __float_as_uint(f);
  unsigned int r = (u + 0x7fffu + ((u >> 16) & 1u)) >> 16;
  return (unsigned short)r;
}

// ---------------- GEMM: feat_v = x @ W_v^T (bf16 MFMA, fp32 accum) ----------
__global__ __launch_bounds__(256) void gemm_feat_kernel(
    const float* __restrict__ x, const float* __restrict__ Ws,
    const float* __restrict__ Wt, const float* __restrict__ Wp,
    unsigned short* __restrict__ feat) {
  __shared__ unsigned short xa[128 * 128];  // [row][k] bf16, XOR-swizzled
  __shared__ unsigned short wb[128 * 128];  // [o][k]  bf16, XOR-swizzled
  const int t = threadIdx.x;
  const int n0 = blockIdx.x * 128;

  // stage x tile (fp32 -> bf16), zeros for OOB rows
  for (int i = 0; i < 16; ++i) {
    int flat = (i * 256 + t) * 4;
    int r = flat >> 7, c = flat & 127;
    float4 val = make_float4(0.f, 0.f, 0.f, 0.f);
    if (n0 + r < N_NODES) val = *(const float4*)(x + (size_t)(n0 + r) * DIM + c);
    int byteoff = (r * 256 + c * 2) ^ ((r & 7) << 4);
    unsigned short* p = (unsigned short*)((char*)xa + byteoff);
    p[0] = f2bf(val.x); p[1] = f2bf(val.y); p[2] = f2bf(val.z); p[3] = f2bf(val.w);
  }

  const int wave = t >> 6, lane = t & 63;
  const int wr = wave >> 1, wc = wave & 1;
  const int lrow = lane & 15;
  const int kgrp = lane >> 4;

  for (int v = 0; v < 3; ++v) {
    const float* W = (v == 0) ? Ws : ((v == 1) ? Wt : Wp);
    __syncthreads();  // x staged / previous view's k-loop done
    for (int i = 0; i < 16; ++i) {
      int flat = (i * 256 + t) * 4;
      int r = flat >> 7, c = flat & 127;
      float4 val = *(const float4*)(W + r * DIM + c);
      int byteoff = (r * 256 + c * 2) ^ ((r & 7) << 4);
      unsigned short* p = (unsigned short*)((char*)wb + byteoff);
      p[0] = f2bf(val.x); p[1] = f2bf(val.y); p[2] = f2bf(val.z); p[3] = f2bf(val.w);
    }
    __syncthreads();

    f32x4 acc[4][4];
    for (int m = 0; m < 4; ++m)
      for (int n = 0; n < 4; ++n) acc[m][n] = (f32x4)0.f;

    for (int ks = 0; ks < 4; ++ks) {
      bf16x8 af[4], bfr[4];
      int kb2 = (ks * 32 + kgrp * 8) * 2;
      for (int m = 0; m < 4; ++m) {
        int r = wr * 64 + m * 16 + lrow;
        af[m] = *(const bf16x8*)((const char*)xa + ((r * 256 + kb2) ^ ((r & 7) << 4)));
      }
      for (int n = 0; n < 4; ++n) {
        int r = wc * 64 + n * 16 + lrow;
        bfr[n] = *(const bf16x8*)((const char*)wb + ((r * 256 + kb2) ^ ((r & 7) << 4)));
      }
      for (int m = 0; m < 4; ++m)
        for (int n = 0; n < 4; ++n)
          acc[m][n] = __builtin_amdgcn_mfma_f32_16x16x32_bf16(af[m], bfr[n], acc[m][n], 0, 0, 0);
    }

    unsigned short* fv = feat + (size_t)v * N_NODES * OUTD;
    for (int m = 0; m < 4; ++m)
      for (int n = 0; n < 4; ++n) {
        int col = wc * 64 + n * 16 + lrow;
        for (int r4 = 0; r4 < 4; ++r4) {
          int row = n0 + wr * 64 + m * 16 + kgrp * 4 + r4;
          if (row < N_NODES) fv[(size_t)row * OUTD + col] = f2bf(acc[m][n][r4]);
        }
      }
  }
}

// ---------------- el/er: per (view, node, head) attention logit halves ------
__global__ __launch_bounds__(256) void elr_kernel(
    const unsigned short* __restrict__ feat,
    const float* __restrict__ al_s, const float* __restrict__ ar_s,
    const float* __restrict__ al_t, const float* __restrict__ ar_t,
    const float* __restrict__ al_p, const float* __restrict__ ar_p,
    float* __restrict__ el, float* __restrict__ er) {
  int idx = blockIdx.x * 256 + threadIdx.x;
  if (idx >= 3 * N_NODES * NH) return;
  int v = idx / (N_NODES * NH);
  int rem = idx - v * (N_NODES * NH);
  int n = rem >> 3, h = rem & 7;
  const float* al = (v == 0) ? al_s : ((v == 1) ? al_t : al_p);
  const float* ar = (v == 0) ? ar_s : ((v == 1) ? ar_t : ar_p);
  const unsigned short* fr = feat + (size_t)v * N_NODES * OUTD + (size_t)n * OUTD + h * NF;
  float accl = 0.f, accr = 0.f;
  for (int f = 0; f < NF; ++f) {
    float fv = bf2f(fr[f]);
    accl += fv * al[h * NF + f];
    accr += fv * ar[h * NF + f];
  }
  el[idx] = accl;
  er[idx] = accr;
}

// ---------------- CSR build -------------------------------------------------
__global__ __launch_bounds__(256) void hist_kernel(
    const int* __restrict__ dst_s, const int* __restrict__ dst_t,
    const int* __restrict__ dst_p, int* __restrict__ counts) {
  int i = blockIdx.x * 256 + threadIdx.x;
  if (i >= 3 * NE) return;
  int v = i / NE, e = i - v * NE;
  const int* d = (v == 0) ? dst_s : ((v == 1) ? dst_t : dst_p);
  atomicAdd(counts + v * N_NODES + d[e], 1);
}

__global__ __launch_bounds__(1024) void scan_kernel(
    const int* __restrict__ counts, int* __restrict__ offs, int* __restrict__ cursor) {
  const int v = blockIdx.x;
  const int* c = counts + v * N_NODES;
  int* o = offs + v * NOFF;
  int* cur = cursor + v * N_NODES;
  __shared__ int sh[1024];
  __shared__ int runsh;
  const int t = threadIdx.x;
  if (t == 0) { o[0] = 0; runsh = 0; }
  __syncthreads();
  for (int base = 0; base < N_NODES; base += 1024) {
    int i = base + t;
    int val = (i < N_NODES) ? c[i] : 0;
    sh[t] = val;
    __syncthreads();
    for (int st = 1; st < 1024; st <<= 1) {
      int add = (t >= st) ? sh[t - st] : 0;
      __syncthreads();
      sh[t] += add;
      __syncthreads();
    }
    int incl = sh[t];
    int runv = runsh;
    if (i < N_NODES) { o[i + 1] = runv + incl; cur[i] = runv + incl - val; }
    __syncthreads();
    if (t == 1023) runsh = runv + sh[1023];
    __syncthreads();
  }
}

__global__ __launch_bounds__(256) void scatter_kernel(
    const int* __restrict__ src_s, const int* __restrict__ dst_s,
    const int* __restrict__ src_t, const int* __restrict__ dst_t,
    const int* __restrict__ src_p, const int* __restrict__ dst_p,
    int* __restrict__ cursor, int* __restrict__ esrc) {
  int i = blockIdx.x * 256 + threadIdx.x;
  if (i >= 3 * NE) return;
  int v = i / NE, e = i - v * NE;
  const int* s = (v == 0) ? src_s : ((v == 1) ? src_t : src_p);
  const int* d = (v == 0) ? dst_s : ((v == 1) ? dst_t : dst_p);
  int pos = atomicAdd(cursor + v * N_NODES + d[e], 1);
  esrc[(size_t)v * NE + pos] = s[e];
}

// ---------------- GAT aggregation: one wave per (view, dst node) ------------
__global__ __launch_bounds__(256) void gat_kernel(
    const int* __restrict__ offs, const int* __restrict__ esrc,
    const float* __restrict__ el, const float* __restrict__ er,
    const unsigned short* __restrict__ feat,
    const float* __restrict__ b_s, const float* __restrict__ b_t,
    const float* __restrict__ b_p, float* __restrict__ views) {
  const int v = blockIdx.y;
  const int n = blockIdx.x * 4 + (threadIdx.x >> 6);
  const int lane = threadIdx.x & 63;
  if (n >= N_NODES) return;
  const int* off_v = offs + v * NOFF;
  const int off0 = off_v[n];
  const int deg = off_v[n + 1] - off0;
  const int h = lane >> 3;      // head this lane handles (matches f0/16 below)
  const int esub = lane & 7;
  const int* es = esrc + (size_t)v * NE + off0;
  const float* el_v = el + (size_t)v * N_NODES * NH;
  const float er_h = er[(size_t)v * N_NODES * NH + (size_t)n * NH + h];

  // phase 1a: per-head max (8 lanes per head march over edges)
  float mx = -1e30f;
  for (int base = 0; base < deg; base += 8) {
    int e = base + esub;
    if (e < deg) {
      int s = es[e];
      float val = el_v[s * NH + h] + er_h;
      val = (val > 0.f) ? val : 0.2f * val;
      mx = fmaxf(mx, val);
    }
  }
  for (int d = 1; d < 8; d <<= 1) mx = fmaxf(mx, __shfl_xor(mx, d, 64));
  // phase 1b: per-head sum of exp
  float sm = 0.f;
  for (int base = 0; base < deg; base += 8) {
    int e = base + esub;
    if (e < deg) {
      int s = es[e];
      float val = el_v[s * NH + h] + er_h;
      val = (val > 0.f) ? val : 0.2f * val;
      sm += __expf(val - mx);
    }
  }
  for (int d = 1; d < 8; d <<= 1) sm += __shfl_xor(sm, d, 64);
  const float inv = 1.0f / sm;

  // phase 2: weighted gather of feat rows (2 output floats per lane)
  const int f0 = lane * 2;
  float acc0 = 0.f, acc1 = 0.f;
  const unsigned short* featv = feat + (size_t)v * N_NODES * OUTD;
  for (int e = 0; e < deg; ++e) {
    int s = es[e];
    float val = el_v[s * NH + h] + er_h;
    val = (val > 0.f) ? val : 0.2f * val;
    float aw = __expf(val - mx) * inv;
    unsigned int pk = *(const unsigned int*)(featv + (size_t)s * OUTD + f0);
    acc0 += aw * bf2f(pk & 0xffffu);
    acc1 += aw * bf2f(pk >> 16);
  }
  const float* bv = (v == 0) ? b_s : ((v == 1) ? b_t : b_p);
  float r0 = acc0 + bv[f0], r1 = acc1 + bv[f0 + 1];
  r0 = (r0 > 0.f) ? r0 : 0.f;
  r1 = (r1 > 0.f) ? r1 : 0.f;
  *(float2*)(views + (size_t)v * N_NODES * OUTD + (size_t)n * OUTD + f0) =
      make_float2(r0, r1);
}

// ---------------- fused reduction: QK logits + Wm dot, per view -------------
__global__ __launch_bounds__(256) void reduce_kernel(
    const float* __restrict__ views, const float* __restrict__ Wq,
    const float* __restrict__ bq, const float* __restrict__ Wk,
    const float* __restrict__ bk, const float* __restrict__ Wm,
    float* __restrict__ logits, float* __restrict__ dsum) {
  const int v = blockIdx.y;
  const int n0 = blockIdx.x * 16;
  __shared__ float Vl[16][132];
  __shared__ float Wql[16][132];
  __shared__ float Wkl[16][132];
  const int t = threadIdx.x;
  {
    int flat = t * 8;
    int r = flat >> 7, c = flat & 127;
    const float* src = views + (size_t)v * N_NODES * OUTD + (size_t)(n0 + r) * OUTD + c;
    float4 a = *(const float4*)(src);
    float4 b = *(const float4*)(src + 4);
    Vl[r][c + 0] = a.x; Vl[r][c + 1] = a.y; Vl[r][c + 2] = a.z; Vl[r][c + 3] = a.w;
    Vl[r][c + 4] = b.x; Vl[r][c + 5] = b.y; Vl[r][c + 6] = b.z; Vl[r][c + 7] = b.w;
    float4 qa = *(const float4*)(Wq + flat);
    float4 qb = *(const float4*)(Wq + flat + 4);
    Wql[r][c + 0] = qa.x; Wql[r][c + 1] = qa.y; Wql[r][c + 2] = qa.z; Wql[r][c + 3] = qa.w;
    Wql[r][c + 4] = qb.x; Wql[r][c + 5] = qb.y; Wql[r][c + 6] = qb.z; Wql[r][c + 7] = qb.w;
    float4 ka = *(const float4*)(Wk + flat);
    float4 kb = *(const float4*)(Wk + flat + 4);
    Wkl[r][c + 0] = ka.x; Wkl[r][c + 1] = ka.y; Wkl[r][c + 2] = ka.z; Wkl[r][c + 3] = ka.w;
    Wkl[r][c + 4] = kb.x; Wkl[r][c + 5] = kb.y; Wkl[r][c + 6] = kb.z; Wkl[r][c + 7] = kb.w;
  }
  __syncthreads();
  const int nl = t >> 4, h = t & 15;
  float q = bq[h], k = bk[h];
  for (int e = 0; e < 128; ++e) {
    float vv = Vl[nl][e];
    q += vv * Wql[h][e];
    k += vv * Wkl[h][e];
  }
  float qk = q * k;
  float dp = 0.f;
  const float* wmrow = Wm + (size_t)(n0 + nl) * OUTD + h * 8;
  for (int e = 0; e < 8; ++e) dp += Vl[nl][h * 8 + e] * wmrow[e];
  for (int d = 1; d < 64; d <<= 1) {
    qk += __shfl_xor(qk, d, 64);
    dp += __shfl_xor(dp, d, 64);
  }
  __shared__ float redq[4], redd[4];
  int wid = t >> 6;
  if ((t & 63) == 0) { redq[wid] = qk; redd[wid] = dp; }
  __syncthreads();
  if (t == 0) {
    atomicAdd(&logits[v], redq[0] + redq[1] + redq[2] + redq[3]);
    atomicAdd(&dsum[v], redd[0] + redd[1] + redd[2] + redd[3]);
  }
}

// ---------------- scalar chain: softmax + sigmoid gates ---------------------
__global__ void scalar_kernel(const float* __restrict__ logits,
                              const float* __restrict__ dsum,
                              const float* __restrict__ bm, float* __restrict__ gc) {
  if (threadIdx.x == 0 && blockIdx.x == 0) {
    const float scale = 1.0f / sqrtf((float)(NF * N_NODES));
    float l0 = logits[0] * scale, l1 = logits[1] * scale, l2 = logits[2] * scale;
    float mx = fmaxf(l0, fmaxf(l1, l2));
    float e0 = __expf(l0 - mx), e1 = __expf(l1 - mx), e2 = __expf(l2 - mx);
    float inv = 1.0f / (e0 + e1 + e2);
    float g0 = 0.8f * e0 * inv + 0.2f;
    float g1 = 0.8f * e1 * inv + 0.2f;
    float g2 = 0.8f * e2 * inv + 0.2f;
    float bmv = bm[0];
    float o0 = 1.0f / (1.0f + __expf(-(g0 * dsum[0] + bmv)));
    float o1 = 1.0f / (1.0f + __expf(-(g1 * dsum[1] + bmv)));
    float o2 = 1.0f / (1.0f + __expf(-(g2 * dsum[2] + bmv)));
    gc[0] = g0; gc[1] = g1; gc[2] = g2;
    gc[3] = o0 * g0; gc[4] = o1 * g1; gc[5] = o2 * g2;
  }
}

// ---------------- epilogue: mv + result -------------------------------------
__global__ __launch_bounds__(256) void final_kernel(
    const float* __restrict__ views, const float* __restrict__ gc,
    float* __restrict__ out) {
  const size_t NT = (size_t)N_NODES * OUTD;
  size_t base = ((size_t)blockIdx.x * 256 + threadIdx.x) * 4;
  if (base >= NT) return;
  float g0 = gc[0], g1 = gc[1], g2 = gc[2], c0 = gc[3], c1 = gc[4], c2 = gc[5];
  float4 a0 = *(const float4*)(views + base);
  float4 a1 = *(const float4*)(views + NT + base);
  float4 a2 = *(const float4*)(views + 2 * NT + base);
  float4 mv;
  mv.x = c0 * a0.x + c1 * a1.x + c2 * a2.x;
  mv.y = c0 * a0.y + c1 * a1.y + c2 * a2.y;
  mv.z = c0 * a0.z + c1 * a1.z + c2 * a2.z;
  mv.w = c0 * a0.w + c1 * a1.w + c2 * a2.w;
  *(float4*)(out + base) = mv;
  float4 r;
  r.x = 0.5f * (g0 * a0.x) + 0.5f * mv.x;
  r.y = 0.5f * (g0 * a0.y) + 0.5f * mv.y;
  r.z = 0.5f * (g0 * a0.z) + 0.5f * mv.z;
  r.w = 0.5f * (g0 * a0.w) + 0.5f * mv.w;
  *(float4*)(out + NT + base) = r;
  r.x = 0.5f * (g1 * a1.x) + 0.5f * mv.x;
  r.y = 0.5f * (g1 * a1.y) + 0.5f * mv.y;
  r.z = 0.5f * (g1 * a1.z) + 0.5f * mv.z;
  r.w = 0.5f * (g1 * a1.w) + 0.5f * mv.w;
  *(float4*)(out + 2 * NT + base) = r;
  r.x = 0.5f * (g2 * a2.x) + 0.5f * mv.x;
  r.y = 0.5f * (g2 * a2.y) + 0.5f * mv.y;
  r.z = 0.5f * (g2 * a2.z) + 0.5f * mv.z;
  r.w = 0.5f * (g2 * a2.w) + 0.5f * mv.w;
  *(float4*)(out + 3 * NT + base) = r;
}

extern "C" void kernel_launch(void* const* d_in, const int* in_sizes, int n_in,
                              void* d_out, int out_size, void* d_ws, size_t ws_size,
                              hipStream_t stream) {
  const float* x = (const float*)d_in[0];
  const int* src_s = (const int*)d_in[1];
  const int* dst_s = (const int*)d_in[2];
  const int* src_t = (const int*)d_in[3];
  const int* dst_t = (const int*)d_in[4];
  const int* src_p = (const int*)d_in[5];
  const int* dst_p = (const int*)d_in[6];
  const float* W_s = (const float*)d_in[7];
  const float* al_s = (const float*)d_in[8];
  const float* ar_s = (const float*)d_in[9];
  const float* b_s = (const float*)d_in[10];
  const float* W_t = (const float*)d_in[11];
  const float* al_t = (const float*)d_in[12];
  const float* ar_t = (const float*)d_in[13];
  const float* b_t = (const float*)d_in[14];
  const float* W_p = (const float*)d_in[15];
  const float* al_p = (const float*)d_in[16];
  const float* ar_p = (const float*)d_in[17];
  const float* b_p = (const float*)d_in[18];
  const float* Wq = (const float*)d_in[19];
  const float* bq = (const float*)d_in[20];
  const float* Wk = (const float*)d_in[21];
  const float* bk = (const float*)d_in[22];
  const float* Wm = (const float*)d_in[23];
  const float* bm = (const float*)d_in[24];
  float* out = (float*)d_out;

  char* ws = (char*)d_ws;
  unsigned short* feat = (unsigned short*)ws;
  float* el = (float*)(ws + 38400000);
  float* er = (float*)(ws + 43200000);
  float* views = (float*)(ws + 48000000);
  int* offs = (int*)(ws + 124800000);
  int* cursor = (int*)(ws + 125400016);
  int* esrc = (int*)(ws + 126000016);
  int* counts = (int*)(ws + 136200016);
  float* scal = (float*)(ws + 136800016);  // logits[3], dsum[3], gc[6]

  hipMemsetAsync(counts, 0, 600000 + 48, stream);

  gemm_feat_kernel<<<dim3(391), dim3(256), 0, stream>>>(x, W_s, W_t, W_p, feat);
  elr_kernel<<<dim3((3 * N_NODES * NH + 255) / 256), dim3(256), 0, stream>>>(
      feat, al_s, ar_s, al_t, ar_t, al_p, ar_p, el, er);
  hist_kernel<<<dim3((3 * NE + 255) / 256), dim3(256), 0, stream>>>(dst_s, dst_t, dst_p, counts);
  scan_kernel<<<dim3(3), dim3(1024), 0, stream>>>(counts, offs, cursor);
  scatter_kernel<<<dim3((3 * NE + 255) / 256), dim3(256), 0, stream>>>(
      src_s, dst_s, src_t, dst_t, src_p, dst_p, cursor, esrc);
  gat_kernel<<<dim3(12500, 3), dim3(256), 0, stream>>>(
      offs, esrc, el, er, feat, b_s, b_t, b_p, views);
  reduce_kernel<<<dim3(3125, 3), dim3(256), 0, stream>>>(
      views, Wq, bq, Wk, bk, Wm, scal, scal + 3);
  scalar_kernel<<<dim3(1), dim3(64), 0, stream>>>(scal, scal + 3, bm, scal + 6);
  final_kernel<<<dim3(6250), dim3(256), 0, stream>>>(views, scal + 6, out);
}

// Round 2
// 865.037 us; speedup vs baseline: 1.3346x; 1.3346x over previous
//
#include <hip/hip_runtime.h>

// MVURE layer: 3x GATConv + view attention fusion.
// Workspace layout (~137 MB):
//   feat   bf16 [3][N][128]   @ 0          (38,400,000 B)
//   el     f32  [3][N][8]     @ 38,400,000 ( 4,800,000 B)
//   er     f32  [3][N][8]     @ 43,200,000 ( 4,800,000 B)
//   views  f32  [3][N][128]   @ 48,000,000 (76,800,000 B)
//     (scan temporaries linc/bsum/cpref overlay the views region; they are
//      fully consumed before gat_kernel writes views)
//   offs   i32  [3][N+1]      @ 124,800,000 (600,016 B padded)
//   cursor i32  [3][N]        @ 125,400,016 (600,000 B)
//   esrc   i32  [3][E]        @ 126,000,016 (10,200,000 B)
//   counts i32  [3][N]        @ 136,200,016 (600,000 B)
//   scal   f32  logits[3],d[3],gc[6] @ 136,800,016 (48 B)

#define N_NODES 50000
#define DIM 128
#define OUTD 128
#define NH 8
#define NF 16
#define NE 850000            // 800000 random + 50000 self loops
#define NOFF 50001
#define NCHUNK 50            // ceil(50000/1024)
#define NBLK (3 * NCHUNK)    // 150 scan blocks

typedef float f32x4 __attribute__((ext_vector_type(4)));
typedef __bf16 bf16x8 __attribute__((ext_vector_type(8)));

static __device__ __forceinline__ float bf2f_lo(unsigned int u) {
  return __uint_as_float(u << 16);
}
static __device__ __forceinline__ float bf2f_hi(unsigned int u) {
  return __uint_as_float(u & 0xffff0000u);
}
static __device__ __forceinline__ unsigned short f2bf(float f) {
  unsigned int u = __float_as_uint(f);
  unsigned int r = (u + 0x7fffu + ((u >> 16) & 1u)) >> 16;
  return (unsigned short)r;
}

// ---------------- GEMM: feat_v = x @ W_v^T (bf16 MFMA, fp32 accum) ----------
__global__ __launch_bounds__(256) void gemm_feat_kernel(
    const float* __restrict__ x, const float* __restrict__ Ws,
    const float* __restrict__ Wt, const float* __restrict__ Wp,
    unsigned short* __restrict__ feat) {
  __shared__ unsigned short xa[128 * 128];  // [row][k] bf16, XOR-swizzled
  __shared__ unsigned short wb[128 * 128];  // [o][k]  bf16, XOR-swizzled
  const int t = threadIdx.x;
  const int n0 = blockIdx.x * 128;

  for (int i = 0; i < 16; ++i) {
    int flat = (i * 256 + t) * 4;
    int r = flat >> 7, c = flat & 127;
    float4 val = make_float4(0.f, 0.f, 0.f, 0.f);
    if (n0 + r < N_NODES) val = *(const float4*)(x + (size_t)(n0 + r) * DIM + c);
    int byteoff = (r * 256 + c * 2) ^ ((r & 7) << 4);
    unsigned short* p = (unsigned short*)((char*)xa + byteoff);
    p[0] = f2bf(val.x); p[1] = f2bf(val.y); p[2] = f2bf(val.z); p[3] = f2bf(val.w);
  }

  const int wave = t >> 6, lane = t & 63;
  const int wr = wave >> 1, wc = wave & 1;
  const int lrow = lane & 15;
  const int kgrp = lane >> 4;

  for (int v = 0; v < 3; ++v) {
    const float* W = (v == 0) ? Ws : ((v == 1) ? Wt : Wp);
    __syncthreads();
    for (int i = 0; i < 16; ++i) {
      int flat = (i * 256 + t) * 4;
      int r = flat >> 7, c = flat & 127;
      float4 val = *(const float4*)(W + r * DIM + c);
      int byteoff = (r * 256 + c * 2) ^ ((r & 7) << 4);
      unsigned short* p = (unsigned short*)((char*)wb + byteoff);
      p[0] = f2bf(val.x); p[1] = f2bf(val.y); p[2] = f2bf(val.z); p[3] = f2bf(val.w);
    }
    __syncthreads();

    f32x4 acc[4][4];
    for (int m = 0; m < 4; ++m)
      for (int n = 0; n < 4; ++n) acc[m][n] = (f32x4)0.f;

    for (int ks = 0; ks < 4; ++ks) {
      bf16x8 af[4], bfr[4];
      int kb2 = (ks * 32 + kgrp * 8) * 2;
      for (int m = 0; m < 4; ++m) {
        int r = wr * 64 + m * 16 + lrow;
        af[m] = *(const bf16x8*)((const char*)xa + ((r * 256 + kb2) ^ ((r & 7) << 4)));
      }
      for (int n = 0; n < 4; ++n) {
        int r = wc * 64 + n * 16 + lrow;
        bfr[n] = *(const bf16x8*)((const char*)wb + ((r * 256 + kb2) ^ ((r & 7) << 4)));
      }
      for (int m = 0; m < 4; ++m)
        for (int n = 0; n < 4; ++n)
          acc[m][n] = __builtin_amdgcn_mfma_f32_16x16x32_bf16(af[m], bfr[n], acc[m][n], 0, 0, 0);
    }

    unsigned short* fv = feat + (size_t)v * N_NODES * OUTD;
    for (int m = 0; m < 4; ++m)
      for (int n = 0; n < 4; ++n) {
        int col = wc * 64 + n * 16 + lrow;
        for (int r4 = 0; r4 < 4; ++r4) {
          int row = n0 + wr * 64 + m * 16 + kgrp * 4 + r4;
          if (row < N_NODES) fv[(size_t)row * OUTD + col] = f2bf(acc[m][n][r4]);
        }
      }
  }
}

// ---------------- el/er: per (view, node, head) attention logit halves ------
__global__ __launch_bounds__(256) void elr_kernel(
    const unsigned short* __restrict__ feat,
    const float* __restrict__ al_s, const float* __restrict__ ar_s,
    const float* __restrict__ al_t, const float* __restrict__ ar_t,
    const float* __restrict__ al_p, const float* __restrict__ ar_p,
    float* __restrict__ el, float* __restrict__ er) {
  int idx = blockIdx.x * 256 + threadIdx.x;
  if (idx >= 3 * N_NODES * NH) return;
  int v = idx / (N_NODES * NH);
  int rem = idx - v * (N_NODES * NH);
  int n = rem >> 3, h = rem & 7;
  const float* al = (v == 0) ? al_s : ((v == 1) ? al_t : al_p);
  const float* ar = (v == 0) ? ar_s : ((v == 1) ? ar_t : ar_p);
  const unsigned short* fr = feat + (size_t)v * N_NODES * OUTD + (size_t)n * OUTD + h * NF;
  float accl = 0.f, accr = 0.f;
  for (int f = 0; f < NF; ++f) {
    float fv = bf2f_lo((unsigned int)fr[f]);
    accl += fv * al[h * NF + f];
    accr += fv * ar[h * NF + f];
  }
  el[idx] = accl;
  er[idx] = accr;
}

// ---------------- CSR build -------------------------------------------------
__global__ __launch_bounds__(256) void hist_kernel(
    const int* __restrict__ dst_s, const int* __restrict__ dst_t,
    const int* __restrict__ dst_p, int* __restrict__ counts) {
  int i = blockIdx.x * 256 + threadIdx.x;
  if (i >= 3 * NE) return;
  int v = i / NE, e = i - v * NE;
  const int* d = (v == 0) ? dst_s : ((v == 1) ? dst_t : dst_p);
  atomicAdd(counts + v * N_NODES + d[e], 1);
}

// two-level scan: 150 parallel local scans -> chunk-prefix scan -> fixup
__global__ __launch_bounds__(1024) void scan1_kernel(
    const int* __restrict__ counts, int* __restrict__ linc, int* __restrict__ bsum) {
  const int b = blockIdx.x;          // 0..149
  const int v = b / NCHUNK, c = b % NCHUNK;
  const int t = threadIdx.x;
  const int i = c * 1024 + t;        // index within view
  int val = (i < N_NODES) ? counts[v * N_NODES + i] : 0;
  __shared__ int sh[1024];
  sh[t] = val;
  __syncthreads();
  for (int st = 1; st < 1024; st <<= 1) {
    int add = (t >= st) ? sh[t - st] : 0;
    __syncthreads();
    sh[t] += add;
    __syncthreads();
  }
  linc[b * 1024 + t] = sh[t];
  if (t == 1023) bsum[b] = sh[1023];
}

__global__ __launch_bounds__(256) void scan2_kernel(
    const int* __restrict__ bsum, int* __restrict__ cpref) {
  // 3 waves, wave w scans its view's 50 chunk sums
  const int w = threadIdx.x >> 6, lane = threadIdx.x & 63;
  if (w >= 3) return;
  int val = (lane < NCHUNK) ? bsum[w * NCHUNK + lane] : 0;
  int incl = val;
  for (int st = 1; st < 64; st <<= 1) {
    int other = __shfl_up(incl, st, 64);
    if (lane >= st) incl += other;
  }
  if (lane < NCHUNK) cpref[w * NCHUNK + lane] = incl - val;  // exclusive
}

__global__ __launch_bounds__(1024) void scan3_kernel(
    const int* __restrict__ counts, const int* __restrict__ linc,
    const int* __restrict__ cpref, int* __restrict__ offs, int* __restrict__ cursor) {
  const int b = blockIdx.x;
  const int v = b / NCHUNK, c = b % NCHUNK;
  const int t = threadIdx.x;
  const int i = c * 1024 + t;
  if (c == 0 && t == 0) offs[v * NOFF] = 0;
  if (i < N_NODES) {
    int total = cpref[b] + linc[b * 1024 + t];
    offs[v * NOFF + i + 1] = total;
    cursor[v * N_NODES + i] = total - counts[v * N_NODES + i];
  }
}

__global__ __launch_bounds__(256) void scatter_kernel(
    const int* __restrict__ src_s, const int* __restrict__ dst_s,
    const int* __restrict__ src_t, const int* __restrict__ dst_t,
    const int* __restrict__ src_p, const int* __restrict__ dst_p,
    int* __restrict__ cursor, int* __restrict__ esrc) {
  int i = blockIdx.x * 256 + threadIdx.x;
  if (i >= 3 * NE) return;
  int v = i / NE, e = i - v * NE;
  const int* s = (v == 0) ? src_s : ((v == 1) ? src_t : src_p);
  const int* d = (v == 0) ? dst_s : ((v == 1) ? dst_t : dst_p);
  int pos = atomicAdd(cursor + v * N_NODES + d[e], 1);
  esrc[(size_t)v * NE + pos] = s[e];
}

// ---------------- GAT aggregation: one wave per (view, dst node) ------------
// Single pass: softmax without max-subtraction (logits bounded ~|2|, exp safe;
// result mathematically identical). 16 lanes x 16B cover one 256B feat row;
// 4 lane-groups x 2-unroll = 8 edges in flight.
__global__ __launch_bounds__(256) void gat_kernel(
    const int* __restrict__ offs, const int* __restrict__ esrc,
    const float* __restrict__ el, const float* __restrict__ er,
    const unsigned short* __restrict__ feat,
    const float* __restrict__ b_s, const float* __restrict__ b_t,
    const float* __restrict__ b_p, float* __restrict__ views) {
  const int v = blockIdx.y;
  const int n = blockIdx.x * 4 + (threadIdx.x >> 6);
  const int lane = threadIdx.x & 63;
  const int g = lane >> 4;       // edge sub-slot 0..3
  const int q = lane & 15;       // feature chunk: covers f = q*8 .. q*8+7
  const int h = q >> 1;          // head of this lane's feature chunk
  const int* off_v = offs + v * NOFF;
  const int off0 = off_v[n];
  const int deg = off_v[n + 1] - off0;   // >= 1 (self loop)
  const int* es = esrc + (size_t)v * NE + off0;
  const float* el_v = el + (size_t)v * N_NODES * NH;
  const float er_h = er[((size_t)v * N_NODES + n) * NH + h];
  const unsigned short* featv = feat + (size_t)v * N_NODES * OUTD;

  float acc[8];
#pragma unroll
  for (int j = 0; j < 8; ++j) acc[j] = 0.f;
  float sm = 0.f;

  for (int base = 0; base < deg; base += 8) {
    int e0 = base + g, e1 = base + 4 + g;
    bool v0 = e0 < deg, v1 = e1 < deg;
    int s0 = es[v0 ? e0 : 0];
    int s1 = es[v1 ? e1 : 0];
    float val0 = el_v[s0 * NH + h] + er_h;
    float val1 = el_v[s1 * NH + h] + er_h;
    uint4 pk0 = *(const uint4*)(featv + s0 * OUTD + q * 8);
    uint4 pk1 = *(const uint4*)(featv + s1 * OUTD + q * 8);
    val0 = (val0 > 0.f) ? val0 : 0.2f * val0;
    val1 = (val1 > 0.f) ? val1 : 0.2f * val1;
    float aw0 = v0 ? __expf(val0) : 0.f;
    float aw1 = v1 ? __expf(val1) : 0.f;
    sm += aw0 + aw1;
    acc[0] += aw0 * bf2f_lo(pk0.x) + aw1 * bf2f_lo(pk1.x);
    acc[1] += aw0 * bf2f_hi(pk0.x) + aw1 * bf2f_hi(pk1.x);
    acc[2] += aw0 * bf2f_lo(pk0.y) + aw1 * bf2f_lo(pk1.y);
    acc[3] += aw0 * bf2f_hi(pk0.y) + aw1 * bf2f_hi(pk1.y);
    acc[4] += aw0 * bf2f_lo(pk0.z) + aw1 * bf2f_lo(pk1.z);
    acc[5] += aw0 * bf2f_hi(pk0.z) + aw1 * bf2f_hi(pk1.z);
    acc[6] += aw0 * bf2f_lo(pk0.w) + aw1 * bf2f_lo(pk1.w);
    acc[7] += aw0 * bf2f_hi(pk0.w) + aw1 * bf2f_hi(pk1.w);
  }

  // reduce over the 4 edge-groups (lanes differing in bits 4,5)
#pragma unroll
  for (int m = 16; m < 64; m <<= 1) {
    sm += __shfl_xor(sm, m, 64);
#pragma unroll
    for (int j = 0; j < 8; ++j) acc[j] += __shfl_xor(acc[j], m, 64);
  }

  if (g == 0) {
    const float inv = 1.0f / sm;
    const float* bv = (v == 0) ? b_s : ((v == 1) ? b_t : b_p);
    float r[8];
#pragma unroll
    for (int j = 0; j < 8; ++j) {
      float x = acc[j] * inv + bv[q * 8 + j];
      r[j] = (x > 0.f) ? x : 0.f;
    }
    float* dst = views + (size_t)v * N_NODES * OUTD + (size_t)n * OUTD + q * 8;
    *(float4*)(dst) = make_float4(r[0], r[1], r[2], r[3]);
    *(float4*)(dst + 4) = make_float4(r[4], r[5], r[6], r[7]);
  }
}

// ---------------- fused reduction: QK logits + Wm dot, per view -------------
__global__ __launch_bounds__(256) void reduce_kernel(
    const float* __restrict__ views, const float* __restrict__ Wq,
    const float* __restrict__ bq, const float* __restrict__ Wk,
    const float* __restrict__ bk, const float* __restrict__ Wm,
    float* __restrict__ logits, float* __restrict__ dsum) {
  const int v = blockIdx.y;
  const int n0 = blockIdx.x * 16;
  __shared__ float Vl[16][132];
  __shared__ float Wql[16][132];
  __shared__ float Wkl[16][132];
  const int t = threadIdx.x;
  {
    int flat = t * 8;
    int r = flat >> 7, c = flat & 127;
    const float* src = views + (size_t)v * N_NODES * OUTD + (size_t)(n0 + r) * OUTD + c;
    float4 a = *(const float4*)(src);
    float4 b = *(const float4*)(src + 4);
    Vl[r][c + 0] = a.x; Vl[r][c + 1] = a.y; Vl[r][c + 2] = a.z; Vl[r][c + 3] = a.w;
    Vl[r][c + 4] = b.x; Vl[r][c + 5] = b.y; Vl[r][c + 6] = b.z; Vl[r][c + 7] = b.w;
    float4 qa = *(const float4*)(Wq + flat);
    float4 qb = *(const float4*)(Wq + flat + 4);
    Wql[r][c + 0] = qa.x; Wql[r][c + 1] = qa.y; Wql[r][c + 2] = qa.z; Wql[r][c + 3] = qa.w;
    Wql[r][c + 4] = qb.x; Wql[r][c + 5] = qb.y; Wql[r][c + 6] = qb.z; Wql[r][c + 7] = qb.w;
    float4 ka = *(const float4*)(Wk + flat);
    float4 kb = *(const float4*)(Wk + flat + 4);
    Wkl[r][c + 0] = ka.x; Wkl[r][c + 1] = ka.y; Wkl[r][c + 2] = ka.z; Wkl[r][c + 3] = ka.w;
    Wkl[r][c + 4] = kb.x; Wkl[r][c + 5] = kb.y; Wkl[r][c + 6] = kb.z; Wkl[r][c + 7] = kb.w;
  }
  __syncthreads();
  const int nl = t >> 4, h = t & 15;
  float q = bq[h], k = bk[h];
  for (int e = 0; e < 128; ++e) {
    float vv = Vl[nl][e];
    q += vv * Wql[h][e];
    k += vv * Wkl[h][e];
  }
  float qk = q * k;
  float dp = 0.f;
  const float* wmrow = Wm + (size_t)(n0 + nl) * OUTD + h * 8;
  for (int e = 0; e < 8; ++e) dp += Vl[nl][h * 8 + e] * wmrow[e];
  for (int d = 1; d < 64; d <<= 1) {
    qk += __shfl_xor(qk, d, 64);
    dp += __shfl_xor(dp, d, 64);
  }
  __shared__ float redq[4], redd[4];
  int wid = t >> 6;
  if ((t & 63) == 0) { redq[wid] = qk; redd[wid] = dp; }
  __syncthreads();
  if (t == 0) {
    atomicAdd(&logits[v], redq[0] + redq[1] + redq[2] + redq[3]);
    atomicAdd(&dsum[v], redd[0] + redd[1] + redd[2] + redd[3]);
  }
}

// ---------------- scalar chain: softmax + sigmoid gates ---------------------
__global__ void scalar_kernel(const float* __restrict__ logits,
                              const float* __restrict__ dsum,
                              const float* __restrict__ bm, float* __restrict__ gc) {
  if (threadIdx.x == 0 && blockIdx.x == 0) {
    const float scale = 1.0f / sqrtf((float)(NF * N_NODES));
    float l0 = logits[0] * scale, l1 = logits[1] * scale, l2 = logits[2] * scale;
    float mx = fmaxf(l0, fmaxf(l1, l2));
    float e0 = __expf(l0 - mx), e1 = __expf(l1 - mx), e2 = __expf(l2 - mx);
    float inv = 1.0f / (e0 + e1 + e2);
    float g0 = 0.8f * e0 * inv + 0.2f;
    float g1 = 0.8f * e1 * inv + 0.2f;
    float g2 = 0.8f * e2 * inv + 0.2f;
    float bmv = bm[0];
    float o0 = 1.0f / (1.0f + __expf(-(g0 * dsum[0] + bmv)));
    float o1 = 1.0f / (1.0f + __expf(-(g1 * dsum[1] + bmv)));
    float o2 = 1.0f / (1.0f + __expf(-(g2 * dsum[2] + bmv)));
    gc[0] = g0; gc[1] = g1; gc[2] = g2;
    gc[3] = o0 * g0; gc[4] = o1 * g1; gc[5] = o2 * g2;
  }
}

// ---------------- epilogue: mv + result -------------------------------------
__global__ __launch_bounds__(256) void final_kernel(
    const float* __restrict__ views, const float* __restrict__ gc,
    float* __restrict__ out) {
  const size_t NT = (size_t)N_NODES * OUTD;
  size_t base = ((size_t)blockIdx.x * 256 + threadIdx.x) * 4;
  if (base >= NT) return;
  float g0 = gc[0], g1 = gc[1], g2 = gc[2], c0 = gc[3], c1 = gc[4], c2 = gc[5];
  float4 a0 = *(const float4*)(views + base);
  float4 a1 = *(const float4*)(views + NT + base);
  float4 a2 = *(const float4*)(views + 2 * NT + base);
  float4 mv;
  mv.x = c0 * a0.x + c1 * a1.x + c2 * a2.x;
  mv.y = c0 * a0.y + c1 * a1.y + c2 * a2.y;
  mv.z = c0 * a0.z + c1 * a1.z + c2 * a2.z;
  mv.w = c0 * a0.w + c1 * a1.w + c2 * a2.w;
  *(float4*)(out + base) = mv;
  float4 r;
  r.x = 0.5f * (g0 * a0.x) + 0.5f * mv.x;
  r.y = 0.5f * (g0 * a0.y) + 0.5f * mv.y;
  r.z = 0.5f * (g0 * a0.z) + 0.5f * mv.z;
  r.w = 0.5f * (g0 * a0.w) + 0.5f * mv.w;
  *(float4*)(out + NT + base) = r;
  r.x = 0.5f * (g1 * a1.x) + 0.5f * mv.x;
  r.y = 0.5f * (g1 * a1.y) + 0.5f * mv.y;
  r.z = 0.5f * (g1 * a1.z) + 0.5f * mv.z;
  r.w = 0.5f * (g1 * a1.w) + 0.5f * mv.w;
  *(float4*)(out + 2 * NT + base) = r;
  r.x = 0.5f * (g2 * a2.x) + 0.5f * mv.x;
  r.y = 0.5f * (g2 * a2.y) + 0.5f * mv.y;
  r.z = 0.5f * (g2 * a2.z) + 0.5f * mv.z;
  r.w = 0.5f * (g2 * a2.w) + 0.5f * mv.w;
  *(float4*)(out + 3 * NT + base) = r;
}

extern "C" void kernel_launch(void* const* d_in, const int* in_sizes, int n_in,
                              void* d_out, int out_size, void* d_ws, size_t ws_size,
                              hipStream_t stream) {
  const float* x = (const float*)d_in[0];
  const int* src_s = (const int*)d_in[1];
  const int* dst_s = (const int*)d_in[2];
  const int* src_t = (const int*)d_in[3];
  const int* dst_t = (const int*)d_in[4];
  const int* src_p = (const int*)d_in[5];
  const int* dst_p = (const int*)d_in[6];
  const float* W_s = (const float*)d_in[7];
  const float* al_s = (const float*)d_in[8];
  const float* ar_s = (const float*)d_in[9];
  const float* b_s = (const float*)d_in[10];
  const float* W_t = (const float*)d_in[11];
  const float* al_t = (const float*)d_in[12];
  const float* ar_t = (const float*)d_in[13];
  const float* b_t = (const float*)d_in[14];
  const float* W_p = (const float*)d_in[15];
  const float* al_p = (const float*)d_in[16];
  const float* ar_p = (const float*)d_in[17];
  const float* b_p = (const float*)d_in[18];
  const float* Wq = (const float*)d_in[19];
  const float* bq = (const float*)d_in[20];
  const float* Wk = (const float*)d_in[21];
  const float* bk = (const float*)d_in[22];
  const float* Wm = (const float*)d_in[23];
  const float* bm = (const float*)d_in[24];
  float* out = (float*)d_out;

  char* ws = (char*)d_ws;
  unsigned short* feat = (unsigned short*)ws;
  float* el = (float*)(ws + 38400000);
  float* er = (float*)(ws + 43200000);
  float* views = (float*)(ws + 48000000);
  int* offs = (int*)(ws + 124800000);
  int* cursor = (int*)(ws + 125400016);
  int* esrc = (int*)(ws + 126000016);
  int* counts = (int*)(ws + 136200016);
  float* scal = (float*)(ws + 136800016);  // logits[3], dsum[3], gc[6]

  // scan temporaries overlay the (not yet written) views buffer
  int* linc = (int*)(ws + 48000000);                 // 150*1024*4 = 614,400 B
  int* bsum = (int*)(ws + 48000000 + 614400);        // 600 B
  int* cpref = (int*)(ws + 48000000 + 616000);       // 600 B

  hipMemsetAsync(counts, 0, 600000 + 48, stream);

  gemm_feat_kernel<<<dim3(391), dim3(256), 0, stream>>>(x, W_s, W_t, W_p, feat);
  elr_kernel<<<dim3((3 * N_NODES * NH + 255) / 256), dim3(256), 0, stream>>>(
      feat, al_s, ar_s, al_t, ar_t, al_p, ar_p, el, er);
  hist_kernel<<<dim3((3 * NE + 255) / 256), dim3(256), 0, stream>>>(dst_s, dst_t, dst_p, counts);
  scan1_kernel<<<dim3(NBLK), dim3(1024), 0, stream>>>(counts, linc, bsum);
  scan2_kernel<<<dim3(1), dim3(256), 0, stream>>>(bsum, cpref);
  scan3_kernel<<<dim3(NBLK), dim3(1024), 0, stream>>>(counts, linc, cpref, offs, cursor);
  scatter_kernel<<<dim3((3 * NE + 255) / 256), dim3(256), 0, stream>>>(
      src_s, dst_s, src_t, dst_t, src_p, dst_p, cursor, esrc);
  gat_kernel<<<dim3(12500, 3), dim3(256), 0, stream>>>(
      offs, esrc, el, er, feat, b_s, b_t, b_p, views);
  reduce_kernel<<<dim3(3125, 3), dim3(256), 0, stream>>>(
      views, Wq, bq, Wk, bk, Wm, scal, scal + 3);
  scalar_kernel<<<dim3(1), dim3(64), 0, stream>>>(scal, scal + 3, bm, scal + 6);
  final_kernel<<<dim3(6250), dim3(256), 0, stream>>>(views, scal + 6, out);
}

// Round 3
// 680.907 us; speedup vs baseline: 1.6955x; 1.2704x over previous
//
#include <hip/hip_runtime.h>

// MVURE layer: 3x GATConv + view attention fusion.
// Workspace layout (~137 MB):
//   feat   bf16 [3][N][128]   @ 0          (38,400,000 B)
//   el     f32  [3][N][8]     @ 38,400,000 ( 4,800,000 B)
//   er     f32  [3][N][8]     @ 43,200,000 ( 4,800,000 B)
//   views  f32  [3][N][128]   @ 48,000,000 (76,800,000 B)
//     (scan temporaries linc/bsum/cpref overlay the views region; consumed
//      before gat_kernel writes views)
//   offs   i32  [3][N+1]      @ 124,800,000 (600,016 B padded)
//   cursor i32  [3][N]        @ 125,400,016 (600,000 B)
//   esrc   i32  [3][E]        @ 126,000,016 (10,200,000 B)
//   counts i32  [3][N]        @ 136,200,016 (600,000 B)
//   scal   f32  logits[3],d[3],gc[6] @ 136,800,016 (48 B)

#define N_NODES 50000
#define DIM 128
#define OUTD 128
#define NH 8
#define NF 16
#define NE 850000            // 800000 random + 50000 self loops
#define NOFF 50001
#define NCHUNK 50            // ceil(50000/1024)
#define NBLK (3 * NCHUNK)    // 150 scan blocks

typedef float f32x4 __attribute__((ext_vector_type(4)));
typedef __bf16 bf16x8 __attribute__((ext_vector_type(8)));
typedef unsigned short u16x8 __attribute__((ext_vector_type(8)));

static __device__ __forceinline__ float bf2f_lo(unsigned int u) {
  return __uint_as_float(u << 16);
}
static __device__ __forceinline__ float bf2f_hi(unsigned int u) {
  return __uint_as_float(u & 0xffff0000u);
}
static __device__ __forceinline__ unsigned short f2bf(float f) {
  unsigned int u = __float_as_uint(f);
  unsigned int r = (u + 0x7fffu + ((u >> 16) & 1u)) >> 16;
  return (unsigned short)r;
}

// ---------------- GEMM: feat_v = x @ W_v^T (bf16 MFMA, fp32 accum) ----------
__global__ __launch_bounds__(256) void gemm_feat_kernel(
    const float* __restrict__ x, const float* __restrict__ Ws,
    const float* __restrict__ Wt, const float* __restrict__ Wp,
    unsigned short* __restrict__ feat) {
  __shared__ unsigned short xa[128 * 128];  // [row][k] bf16, XOR-swizzled
  __shared__ unsigned short wb[128 * 128];  // [o][k]  bf16, XOR-swizzled
  const int t = threadIdx.x;
  const int n0 = blockIdx.x * 128;

  for (int i = 0; i < 16; ++i) {
    int flat = (i * 256 + t) * 4;
    int r = flat >> 7, c = flat & 127;
    float4 val = make_float4(0.f, 0.f, 0.f, 0.f);
    if (n0 + r < N_NODES) val = *(const float4*)(x + (size_t)(n0 + r) * DIM + c);
    int byteoff = (r * 256 + c * 2) ^ ((r & 7) << 4);
    unsigned short* p = (unsigned short*)((char*)xa + byteoff);
    p[0] = f2bf(val.x); p[1] = f2bf(val.y); p[2] = f2bf(val.z); p[3] = f2bf(val.w);
  }

  const int wave = t >> 6, lane = t & 63;
  const int wr = wave >> 1, wc = wave & 1;
  const int lrow = lane & 15;
  const int kgrp = lane >> 4;

  for (int v = 0; v < 3; ++v) {
    const float* W = (v == 0) ? Ws : ((v == 1) ? Wt : Wp);
    __syncthreads();
    for (int i = 0; i < 16; ++i) {
      int flat = (i * 256 + t) * 4;
      int r = flat >> 7, c = flat & 127;
      float4 val = *(const float4*)(W + r * DIM + c);
      int byteoff = (r * 256 + c * 2) ^ ((r & 7) << 4);
      unsigned short* p = (unsigned short*)((char*)wb + byteoff);
      p[0] = f2bf(val.x); p[1] = f2bf(val.y); p[2] = f2bf(val.z); p[3] = f2bf(val.w);
    }
    __syncthreads();

    f32x4 acc[4][4];
    for (int m = 0; m < 4; ++m)
      for (int n = 0; n < 4; ++n) acc[m][n] = (f32x4)0.f;

    for (int ks = 0; ks < 4; ++ks) {
      bf16x8 af[4], bfr[4];
      int kb2 = (ks * 32 + kgrp * 8) * 2;
      for (int m = 0; m < 4; ++m) {
        int r = wr * 64 + m * 16 + lrow;
        af[m] = *(const bf16x8*)((const char*)xa + ((r * 256 + kb2) ^ ((r & 7) << 4)));
      }
      for (int n = 0; n < 4; ++n) {
        int r = wc * 64 + n * 16 + lrow;
        bfr[n] = *(const bf16x8*)((const char*)wb + ((r * 256 + kb2) ^ ((r & 7) << 4)));
      }
      for (int m = 0; m < 4; ++m)
        for (int n = 0; n < 4; ++n)
          acc[m][n] = __builtin_amdgcn_mfma_f32_16x16x32_bf16(af[m], bfr[n], acc[m][n], 0, 0, 0);
    }

    unsigned short* fv = feat + (size_t)v * N_NODES * OUTD;
    for (int m = 0; m < 4; ++m)
      for (int n = 0; n < 4; ++n) {
        int col = wc * 64 + n * 16 + lrow;
        for (int r4 = 0; r4 < 4; ++r4) {
          int row = n0 + wr * 64 + m * 16 + kgrp * 4 + r4;
          if (row < N_NODES) fv[(size_t)row * OUTD + col] = f2bf(acc[m][n][r4]);
        }
      }
  }
}

// ---------------- el/er: per (view, node, head) attention logit halves ------
__global__ __launch_bounds__(256) void elr_kernel(
    const unsigned short* __restrict__ feat,
    const float* __restrict__ al_s, const float* __restrict__ ar_s,
    const float* __restrict__ al_t, const float* __restrict__ ar_t,
    const float* __restrict__ al_p, const float* __restrict__ ar_p,
    float* __restrict__ el, float* __restrict__ er) {
  int idx = blockIdx.x * 256 + threadIdx.x;
  if (idx >= 3 * N_NODES * NH) return;
  int v = idx / (N_NODES * NH);
  int rem = idx - v * (N_NODES * NH);
  int n = rem >> 3, h = rem & 7;
  const float* al = (v == 0) ? al_s : ((v == 1) ? al_t : al_p);
  const float* ar = (v == 0) ? ar_s : ((v == 1) ? ar_t : ar_p);
  const unsigned short* fr = feat + (size_t)v * N_NODES * OUTD + (size_t)n * OUTD + h * NF;
  uint4 a = *(const uint4*)(fr);
  uint4 b = *(const uint4*)(fr + 8);
  float fv[16];
  fv[0] = bf2f_lo(a.x); fv[1] = bf2f_hi(a.x); fv[2] = bf2f_lo(a.y); fv[3] = bf2f_hi(a.y);
  fv[4] = bf2f_lo(a.z); fv[5] = bf2f_hi(a.z); fv[6] = bf2f_lo(a.w); fv[7] = bf2f_hi(a.w);
  fv[8] = bf2f_lo(b.x); fv[9] = bf2f_hi(b.x); fv[10] = bf2f_lo(b.y); fv[11] = bf2f_hi(b.y);
  fv[12] = bf2f_lo(b.z); fv[13] = bf2f_hi(b.z); fv[14] = bf2f_lo(b.w); fv[15] = bf2f_hi(b.w);
  float accl = 0.f, accr = 0.f;
#pragma unroll
  for (int f = 0; f < NF; ++f) {
    accl += fv[f] * al[h * NF + f];
    accr += fv[f] * ar[h * NF + f];
  }
  el[idx] = accl;
  er[idx] = accr;
}

// ---------------- CSR build -------------------------------------------------
__global__ __launch_bounds__(256) void hist_kernel(
    const int* __restrict__ dst_s, const int* __restrict__ dst_t,
    const int* __restrict__ dst_p, int* __restrict__ counts) {
  int i = blockIdx.x * 256 + threadIdx.x;
  if (i >= 3 * NE) return;
  int v = i / NE, e = i - v * NE;
  const int* d = (v == 0) ? dst_s : ((v == 1) ? dst_t : dst_p);
  atomicAdd(counts + v * N_NODES + d[e], 1);
}

// two-level scan: 150 parallel local scans -> chunk-prefix scan -> fixup
__global__ __launch_bounds__(1024) void scan1_kernel(
    const int* __restrict__ counts, int* __restrict__ linc, int* __restrict__ bsum) {
  const int b = blockIdx.x;          // 0..149
  const int v = b / NCHUNK, c = b % NCHUNK;
  const int t = threadIdx.x;
  const int i = c * 1024 + t;        // index within view
  int val = (i < N_NODES) ? counts[v * N_NODES + i] : 0;
  __shared__ int sh[1024];
  sh[t] = val;
  __syncthreads();
  for (int st = 1; st < 1024; st <<= 1) {
    int add = (t >= st) ? sh[t - st] : 0;
    __syncthreads();
    sh[t] += add;
    __syncthreads();
  }
  linc[b * 1024 + t] = sh[t];
  if (t == 1023) bsum[b] = sh[1023];
}

__global__ __launch_bounds__(256) void scan2_kernel(
    const int* __restrict__ bsum, int* __restrict__ cpref) {
  const int w = threadIdx.x >> 6, lane = threadIdx.x & 63;
  if (w >= 3) return;
  int val = (lane < NCHUNK) ? bsum[w * NCHUNK + lane] : 0;
  int incl = val;
  for (int st = 1; st < 64; st <<= 1) {
    int other = __shfl_up(incl, st, 64);
    if (lane >= st) incl += other;
  }
  if (lane < NCHUNK) cpref[w * NCHUNK + lane] = incl - val;  // exclusive
}

__global__ __launch_bounds__(1024) void scan3_kernel(
    const int* __restrict__ counts, const int* __restrict__ linc,
    const int* __restrict__ cpref, int* __restrict__ offs, int* __restrict__ cursor) {
  const int b = blockIdx.x;
  const int v = b / NCHUNK, c = b % NCHUNK;
  const int t = threadIdx.x;
  const int i = c * 1024 + t;
  if (c == 0 && t == 0) offs[v * NOFF] = 0;
  if (i < N_NODES) {
    int total = cpref[b] + linc[b * 1024 + t];
    offs[v * NOFF + i + 1] = total;
    cursor[v * N_NODES + i] = total - counts[v * N_NODES + i];
  }
}

__global__ __launch_bounds__(256) void scatter_kernel(
    const int* __restrict__ src_s, const int* __restrict__ dst_s,
    const int* __restrict__ src_t, const int* __restrict__ dst_t,
    const int* __restrict__ src_p, const int* __restrict__ dst_p,
    int* __restrict__ cursor, int* __restrict__ esrc) {
  int i = blockIdx.x * 256 + threadIdx.x;
  if (i >= 3 * NE) return;
  int v = i / NE, e = i - v * NE;
  const int* s = (v == 0) ? src_s : ((v == 1) ? src_t : src_p);
  const int* d = (v == 0) ? dst_s : ((v == 1) ? dst_t : dst_p);
  int pos = atomicAdd(cursor + v * N_NODES + d[e], 1);
  esrc[(size_t)v * NE + pos] = s[e];
}

// ---------------- GAT aggregation: one wave per (view, dst node) ------------
__global__ __launch_bounds__(256) void gat_kernel(
    const int* __restrict__ offs, const int* __restrict__ esrc,
    const float* __restrict__ el, const float* __restrict__ er,
    const unsigned short* __restrict__ feat,
    const float* __restrict__ b_s, const float* __restrict__ b_t,
    const float* __restrict__ b_p, float* __restrict__ views) {
  const int v = blockIdx.y;
  const int n = blockIdx.x * 4 + (threadIdx.x >> 6);
  const int lane = threadIdx.x & 63;
  const int g = lane >> 4;       // edge sub-slot 0..3
  const int q = lane & 15;       // feature chunk: covers f = q*8 .. q*8+7
  const int h = q >> 1;          // head of this lane's feature chunk
  const int* off_v = offs + v * NOFF;
  const int off0 = off_v[n];
  const int deg = off_v[n + 1] - off0;   // >= 1 (self loop)
  const int* es = esrc + (size_t)v * NE + off0;
  const float* el_v = el + (size_t)v * N_NODES * NH;
  const float er_h = er[((size_t)v * N_NODES + n) * NH + h];
  const unsigned short* featv = feat + (size_t)v * N_NODES * OUTD;

  float acc[8];
#pragma unroll
  for (int j = 0; j < 8; ++j) acc[j] = 0.f;
  float sm = 0.f;

  for (int base = 0; base < deg; base += 8) {
    int e0 = base + g, e1 = base + 4 + g;
    bool v0 = e0 < deg, v1 = e1 < deg;
    int s0 = es[v0 ? e0 : 0];
    int s1 = es[v1 ? e1 : 0];
    float val0 = el_v[s0 * NH + h] + er_h;
    float val1 = el_v[s1 * NH + h] + er_h;
    uint4 pk0 = *(const uint4*)(featv + s0 * OUTD + q * 8);
    uint4 pk1 = *(const uint4*)(featv + s1 * OUTD + q * 8);
    val0 = (val0 > 0.f) ? val0 : 0.2f * val0;
    val1 = (val1 > 0.f) ? val1 : 0.2f * val1;
    float aw0 = v0 ? __expf(val0) : 0.f;
    float aw1 = v1 ? __expf(val1) : 0.f;
    sm += aw0 + aw1;
    acc[0] += aw0 * bf2f_lo(pk0.x) + aw1 * bf2f_lo(pk1.x);
    acc[1] += aw0 * bf2f_hi(pk0.x) + aw1 * bf2f_hi(pk1.x);
    acc[2] += aw0 * bf2f_lo(pk0.y) + aw1 * bf2f_lo(pk1.y);
    acc[3] += aw0 * bf2f_hi(pk0.y) + aw1 * bf2f_hi(pk1.y);
    acc[4] += aw0 * bf2f_lo(pk0.z) + aw1 * bf2f_lo(pk1.z);
    acc[5] += aw0 * bf2f_hi(pk0.z) + aw1 * bf2f_hi(pk1.z);
    acc[6] += aw0 * bf2f_lo(pk0.w) + aw1 * bf2f_lo(pk1.w);
    acc[7] += aw0 * bf2f_hi(pk0.w) + aw1 * bf2f_hi(pk1.w);
  }

#pragma unroll
  for (int m = 16; m < 64; m <<= 1) {
    sm += __shfl_xor(sm, m, 64);
#pragma unroll
    for (int j = 0; j < 8; ++j) acc[j] += __shfl_xor(acc[j], m, 64);
  }

  if (g == 0) {
    const float inv = 1.0f / sm;
    const float* bv = (v == 0) ? b_s : ((v == 1) ? b_t : b_p);
    float r[8];
#pragma unroll
    for (int j = 0; j < 8; ++j) {
      float x = acc[j] * inv + bv[q * 8 + j];
      r[j] = (x > 0.f) ? x : 0.f;
    }
    float* dst = views + (size_t)v * N_NODES * OUTD + (size_t)n * OUTD + q * 8;
    *(float4*)(dst) = make_float4(r[0], r[1], r[2], r[3]);
    *(float4*)(dst + 4) = make_float4(r[4], r[5], r[6], r[7]);
  }
}

// ---- fused view-reduction: logits[v] = sum_n (V Wq^T + bq).(V Wk^T + bk),
//      dsum[v] = sum(V .* Wm)  — MFMA for the skinny GEMMs, fp32 for Wm dot.
__global__ __launch_bounds__(256) void viewred_kernel(
    const float* __restrict__ views, const float* __restrict__ Wq,
    const float* __restrict__ bq, const float* __restrict__ Wk,
    const float* __restrict__ bk, const float* __restrict__ Wm,
    float* __restrict__ logits, float* __restrict__ dsum) {
  __shared__ unsigned short vt[128 * 128];  // V tile bf16, XOR-swizzled
  __shared__ unsigned short wq[16 * 128];   // Wq bf16, XOR-swizzled
  __shared__ unsigned short wk[16 * 128];
  __shared__ float redq[4], redd[4];
  const int v = blockIdx.y;
  const int n0 = blockIdx.x * 128;
  const int t = threadIdx.x;
  const float* Vv = views + (size_t)v * N_NODES * OUTD;

  // stage Wq/Wk (16x128) as bf16 B-operands
  {
    int flat = t * 8;
    int r = flat >> 7, c = flat & 127;
    int byteoff = (r * 256 + c * 2) ^ ((r & 7) << 4);
    float4 qa = *(const float4*)(Wq + flat);
    float4 qb = *(const float4*)(Wq + flat + 4);
    u16x8 oq;
    oq[0] = f2bf(qa.x); oq[1] = f2bf(qa.y); oq[2] = f2bf(qa.z); oq[3] = f2bf(qa.w);
    oq[4] = f2bf(qb.x); oq[5] = f2bf(qb.y); oq[6] = f2bf(qb.z); oq[7] = f2bf(qb.w);
    *(u16x8*)((char*)wq + byteoff) = oq;
    float4 ka = *(const float4*)(Wk + flat);
    float4 kb = *(const float4*)(Wk + flat + 4);
    u16x8 ok;
    ok[0] = f2bf(ka.x); ok[1] = f2bf(ka.y); ok[2] = f2bf(ka.z); ok[3] = f2bf(ka.w);
    ok[4] = f2bf(kb.x); ok[5] = f2bf(kb.y); ok[6] = f2bf(kb.z); ok[7] = f2bf(kb.w);
    *(u16x8*)((char*)wk + byteoff) = ok;
  }

  // stage V tile (fp32 -> bf16) and accumulate dp = sum(V .* Wm) in fp32
  float dp = 0.f;
  for (int i = 0; i < 8; ++i) {
    int flat = (i * 256 + t) * 8;
    int r = flat >> 7, c = flat & 127;
    int row = n0 + r;
    u16x8 o = (u16x8)0;
    if (row < N_NODES) {
      size_t goff = (size_t)row * OUTD + c;
      float4 a = *(const float4*)(Vv + goff);
      float4 b = *(const float4*)(Vv + goff + 4);
      float4 wa = *(const float4*)(Wm + goff);
      float4 wb2 = *(const float4*)(Wm + goff + 4);
      dp += a.x * wa.x + a.y * wa.y + a.z * wa.z + a.w * wa.w;
      dp += b.x * wb2.x + b.y * wb2.y + b.z * wb2.z + b.w * wb2.w;
      o[0] = f2bf(a.x); o[1] = f2bf(a.y); o[2] = f2bf(a.z); o[3] = f2bf(a.w);
      o[4] = f2bf(b.x); o[5] = f2bf(b.y); o[6] = f2bf(b.z); o[7] = f2bf(b.w);
    }
    int byteoff = (r * 256 + c * 2) ^ ((r & 7) << 4);
    *(u16x8*)((char*)vt + byteoff) = o;
  }
  __syncthreads();

  // MFMA: Q-tile and K-tile for 2 m-tiles per wave, then qk partial
  const int wave = t >> 6, lane = t & 63;
  const int lrow = lane & 15;
  const int kgrp = lane >> 4;
  const float bqv = bq[lrow];
  const float bkv = bk[lrow];
  float qk = 0.f;

  f32x4 accQ[2], accK[2];
  accQ[0] = (f32x4)0.f; accQ[1] = (f32x4)0.f;
  accK[0] = (f32x4)0.f; accK[1] = (f32x4)0.f;
  for (int ks = 0; ks < 4; ++ks) {
    int kb2 = (ks * 32 + kgrp * 8) * 2;
    int rb = lrow;  // B row = output col (h)
    bf16x8 bqf = *(const bf16x8*)((const char*)wq + ((rb * 256 + kb2) ^ ((rb & 7) << 4)));
    bf16x8 bkf = *(const bf16x8*)((const char*)wk + ((rb * 256 + kb2) ^ ((rb & 7) << 4)));
#pragma unroll
    for (int m = 0; m < 2; ++m) {
      int r = (wave * 2 + m) * 16 + lrow;
      bf16x8 af = *(const bf16x8*)((const char*)vt + ((r * 256 + kb2) ^ ((r & 7) << 4)));
      accQ[m] = __builtin_amdgcn_mfma_f32_16x16x32_bf16(af, bqf, accQ[m], 0, 0, 0);
      accK[m] = __builtin_amdgcn_mfma_f32_16x16x32_bf16(af, bkf, accK[m], 0, 0, 0);
    }
  }
#pragma unroll
  for (int m = 0; m < 2; ++m) {
#pragma unroll
    for (int j = 0; j < 4; ++j) {
      int row = n0 + (wave * 2 + m) * 16 + kgrp * 4 + j;
      if (row < N_NODES) qk += (accQ[m][j] + bqv) * (accK[m][j] + bkv);
    }
  }

  // block reduction of qk and dp
#pragma unroll
  for (int m = 1; m < 64; m <<= 1) {
    qk += __shfl_xor(qk, m, 64);
    dp += __shfl_xor(dp, m, 64);
  }
  if (lane == 0) { redq[wave] = qk; redd[wave] = dp; }
  __syncthreads();
  if (t == 0) {
    atomicAdd(&logits[v], redq[0] + redq[1] + redq[2] + redq[3]);
    atomicAdd(&dsum[v], redd[0] + redd[1] + redd[2] + redd[3]);
  }
}

// ---------------- scalar chain: softmax + sigmoid gates ---------------------
__global__ void scalar_kernel(const float* __restrict__ logits,
                              const float* __restrict__ dsum,
                              const float* __restrict__ bm, float* __restrict__ gc) {
  if (threadIdx.x == 0 && blockIdx.x == 0) {
    const float scale = 1.0f / sqrtf((float)(NF * N_NODES));
    float l0 = logits[0] * scale, l1 = logits[1] * scale, l2 = logits[2] * scale;
    float mx = fmaxf(l0, fmaxf(l1, l2));
    float e0 = __expf(l0 - mx), e1 = __expf(l1 - mx), e2 = __expf(l2 - mx);
    float inv = 1.0f / (e0 + e1 + e2);
    float g0 = 0.8f * e0 * inv + 0.2f;
    float g1 = 0.8f * e1 * inv + 0.2f;
    float g2 = 0.8f * e2 * inv + 0.2f;
    float bmv = bm[0];
    float o0 = 1.0f / (1.0f + __expf(-(g0 * dsum[0] + bmv)));
    float o1 = 1.0f / (1.0f + __expf(-(g1 * dsum[1] + bmv)));
    float o2 = 1.0f / (1.0f + __expf(-(g2 * dsum[2] + bmv)));
    gc[0] = g0; gc[1] = g1; gc[2] = g2;
    gc[3] = o0 * g0; gc[4] = o1 * g1; gc[5] = o2 * g2;
  }
}

// ---------------- epilogue: mv + result -------------------------------------
__global__ __launch_bounds__(256) void final_kernel(
    const float* __restrict__ views, const float* __restrict__ gc,
    float* __restrict__ out) {
  const size_t NT = (size_t)N_NODES * OUTD;
  size_t base = ((size_t)blockIdx.x * 256 + threadIdx.x) * 4;
  if (base >= NT) return;
  float g0 = gc[0], g1 = gc[1], g2 = gc[2], c0 = gc[3], c1 = gc[4], c2 = gc[5];
  float4 a0 = *(const float4*)(views + base);
  float4 a1 = *(const float4*)(views + NT + base);
  float4 a2 = *(const float4*)(views + 2 * NT + base);
  float4 mv;
  mv.x = c0 * a0.x + c1 * a1.x + c2 * a2.x;
  mv.y = c0 * a0.y + c1 * a1.y + c2 * a2.y;
  mv.z = c0 * a0.z + c1 * a1.z + c2 * a2.z;
  mv.w = c0 * a0.w + c1 * a1.w + c2 * a2.w;
  *(float4*)(out + base) = mv;
  float4 r;
  r.x = 0.5f * (g0 * a0.x) + 0.5f * mv.x;
  r.y = 0.5f * (g0 * a0.y) + 0.5f * mv.y;
  r.z = 0.5f * (g0 * a0.z) + 0.5f * mv.z;
  r.w = 0.5f * (g0 * a0.w) + 0.5f * mv.w;
  *(float4*)(out + NT + base) = r;
  r.x = 0.5f * (g1 * a1.x) + 0.5f * mv.x;
  r.y = 0.5f * (g1 * a1.y) + 0.5f * mv.y;
  r.z = 0.5f * (g1 * a1.z) + 0.5f * mv.z;
  r.w = 0.5f * (g1 * a1.w) + 0.5f * mv.w;
  *(float4*)(out + 2 * NT + base) = r;
  r.x = 0.5f * (g2 * a2.x) + 0.5f * mv.x;
  r.y = 0.5f * (g2 * a2.y) + 0.5f * mv.y;
  r.z = 0.5f * (g2 * a2.z) + 0.5f * mv.z;
  r.w = 0.5f * (g2 * a2.w) + 0.5f * mv.w;
  *(float4*)(out + 3 * NT + base) = r;
}

extern "C" void kernel_launch(void* const* d_in, const int* in_sizes, int n_in,
                              void* d_out, int out_size, void* d_ws, size_t ws_size,
                              hipStream_t stream) {
  const float* x = (const float*)d_in[0];
  const int* src_s = (const int*)d_in[1];
  const int* dst_s = (const int*)d_in[2];
  const int* src_t = (const int*)d_in[3];
  const int* dst_t = (const int*)d_in[4];
  const int* src_p = (const int*)d_in[5];
  const int* dst_p = (const int*)d_in[6];
  const float* W_s = (const float*)d_in[7];
  const float* al_s = (const float*)d_in[8];
  const float* ar_s = (const float*)d_in[9];
  const float* b_s = (const float*)d_in[10];
  const float* W_t = (const float*)d_in[11];
  const float* al_t = (const float*)d_in[12];
  const float* ar_t = (const float*)d_in[13];
  const float* b_t = (const float*)d_in[14];
  const float* W_p = (const float*)d_in[15];
  const float* al_p = (const float*)d_in[16];
  const float* ar_p = (const float*)d_in[17];
  const float* b_p = (const float*)d_in[18];
  const float* Wq = (const float*)d_in[19];
  const float* bq = (const float*)d_in[20];
  const float* Wk = (const float*)d_in[21];
  const float* bk = (const float*)d_in[22];
  const float* Wm = (const float*)d_in[23];
  const float* bm = (const float*)d_in[24];
  float* out = (float*)d_out;

  char* ws = (char*)d_ws;
  unsigned short* feat = (unsigned short*)ws;
  float* el = (float*)(ws + 38400000);
  float* er = (float*)(ws + 43200000);
  float* views = (float*)(ws + 48000000);
  int* offs = (int*)(ws + 124800000);
  int* cursor = (int*)(ws + 125400016);
  int* esrc = (int*)(ws + 126000016);
  int* counts = (int*)(ws + 136200016);
  float* scal = (float*)(ws + 136800016);  // logits[3], dsum[3], gc[6]

  // scan temporaries overlay the (not yet written) views buffer
  int* linc = (int*)(ws + 48000000);
  int* bsum = (int*)(ws + 48000000 + 614400);
  int* cpref = (int*)(ws + 48000000 + 616000);

  hipMemsetAsync(counts, 0, 600000 + 48, stream);

  gemm_feat_kernel<<<dim3(391), dim3(256), 0, stream>>>(x, W_s, W_t, W_p, feat);
  elr_kernel<<<dim3((3 * N_NODES * NH + 255) / 256), dim3(256), 0, stream>>>(
      feat, al_s, ar_s, al_t, ar_t, al_p, ar_p, el, er);
  hist_kernel<<<dim3((3 * NE + 255) / 256), dim3(256), 0, stream>>>(dst_s, dst_t, dst_p, counts);
  scan1_kernel<<<dim3(NBLK), dim3(1024), 0, stream>>>(counts, linc, bsum);
  scan2_kernel<<<dim3(1), dim3(256), 0, stream>>>(bsum, cpref);
  scan3_kernel<<<dim3(NBLK), dim3(1024), 0, stream>>>(counts, linc, cpref, offs, cursor);
  scatter_kernel<<<dim3((3 * NE + 255) / 256), dim3(256), 0, stream>>>(
      src_s, dst_s, src_t, dst_t, src_p, dst_p, cursor, esrc);
  gat_kernel<<<dim3(12500, 3), dim3(256), 0, stream>>>(
      offs, esrc, el, er, feat, b_s, b_t, b_p, views);
  viewred_kernel<<<dim3(391, 3), dim3(256), 0, stream>>>(
      views, Wq, bq, Wk, bk, Wm, scal, scal + 3);
  scalar_kernel<<<dim3(1), dim3(64), 0, stream>>>(scal, scal + 3, bm, scal + 6);
  final_kernel<<<dim3(6250), dim3(256), 0, stream>>>(views, scal + 6, out);
}

// Round 4
// 621.792 us; speedup vs baseline: 1.8567x; 1.0951x over previous
//
#include <hip/hip_runtime.h>

// MVURE layer: 3x GATConv + view attention fusion.
// Workspace layout (~137 MB):
//   feat   bf16 [3][N][128]   @ 0          (38,400,000 B)
//   el     f32  [3][N][8]     @ 38,400,000 ( 4,800,000 B)
//   er     f32  [3][N][8]     @ 43,200,000 ( 4,800,000 B)
//   views  f32  [3][N][128]   @ 48,000,000 (76,800,000 B)
//     overlays (consumed before gat_kernel writes views):
//       linc/bsum/cpref scan temps @ views+0 .. +617,000
//       gbin  u32 [3][64][18432] @ ws+49,000,000 (14,155,776 B)
//   offs   i32  [3][N+1]      @ 124,800,000 (600,016 B padded)
//   cursor i32  [3][N]        @ 125,400,016 (600,000 B)
//   esrc   i32  [3][E]        @ 126,000,016 (10,200,000 B)
//   counts i32  [3][N]        @ 136,200,016 (600,000 B)
//   gtail  i32  [3][64]       @ 136,800,016 (768 B)
//   scal   f32  logits[3],d[3],gc[6] @ 136,800,784 (48 B)

#define N_NODES 50000
#define DIM 128
#define OUTD 128
#define NH 8
#define NF 16
#define NE 850000            // 800000 random + 50000 self loops
#define NOFF 50001
#define NCHUNK 50            // ceil(50000/1024)
#define NBLK (3 * NCHUNK)    // 150 scan blocks
#define NBUCK 49             // dst>>10 buckets (1024-node windows)
#define BCAP 18432           // per-bucket capacity (mean 17408, +8 sigma)
#define BIN_EPT 8
#define BIN_EPB 2048         // 256 threads * 8 edges
#define NSPLIT 8             // blocks per bucket in local passes

typedef float f32x4 __attribute__((ext_vector_type(4)));
typedef __bf16 bf16x8 __attribute__((ext_vector_type(8)));
typedef unsigned short u16x8 __attribute__((ext_vector_type(8)));

static __device__ __forceinline__ float bf2f_lo(unsigned int u) {
  return __uint_as_float(u << 16);
}
static __device__ __forceinline__ float bf2f_hi(unsigned int u) {
  return __uint_as_float(u & 0xffff0000u);
}
static __device__ __forceinline__ unsigned short f2bf(float f) {
  unsigned int u = __float_as_uint(f);
  unsigned int r = (u + 0x7fffu + ((u >> 16) & 1u)) >> 16;
  return (unsigned short)r;
}

// ---------------- GEMM: feat_v = x @ W_v^T (bf16 MFMA, fp32 accum) ----------
__global__ __launch_bounds__(256) void gemm_feat_kernel(
    const float* __restrict__ x, const float* __restrict__ Ws,
    const float* __restrict__ Wt, const float* __restrict__ Wp,
    unsigned short* __restrict__ feat) {
  __shared__ unsigned short xa[128 * 128];  // [row][k] bf16, XOR-swizzled
  __shared__ unsigned short wb[128 * 128];  // [o][k]  bf16, XOR-swizzled
  const int t = threadIdx.x;
  const int n0 = blockIdx.x * 128;

  for (int i = 0; i < 16; ++i) {
    int flat = (i * 256 + t) * 4;
    int r = flat >> 7, c = flat & 127;
    float4 val = make_float4(0.f, 0.f, 0.f, 0.f);
    if (n0 + r < N_NODES) val = *(const float4*)(x + (size_t)(n0 + r) * DIM + c);
    int byteoff = (r * 256 + c * 2) ^ ((r & 7) << 4);
    unsigned short* p = (unsigned short*)((char*)xa + byteoff);
    p[0] = f2bf(val.x); p[1] = f2bf(val.y); p[2] = f2bf(val.z); p[3] = f2bf(val.w);
  }

  const int wave = t >> 6, lane = t & 63;
  const int wr = wave >> 1, wc = wave & 1;
  const int lrow = lane & 15;
  const int kgrp = lane >> 4;

  for (int v = 0; v < 3; ++v) {
    const float* W = (v == 0) ? Ws : ((v == 1) ? Wt : Wp);
    __syncthreads();
    for (int i = 0; i < 16; ++i) {
      int flat = (i * 256 + t) * 4;
      int r = flat >> 7, c = flat & 127;
      float4 val = *(const float4*)(W + r * DIM + c);
      int byteoff = (r * 256 + c * 2) ^ ((r & 7) << 4);
      unsigned short* p = (unsigned short*)((char*)wb + byteoff);
      p[0] = f2bf(val.x); p[1] = f2bf(val.y); p[2] = f2bf(val.z); p[3] = f2bf(val.w);
    }
    __syncthreads();

    f32x4 acc[4][4];
    for (int m = 0; m < 4; ++m)
      for (int n = 0; n < 4; ++n) acc[m][n] = (f32x4)0.f;

    for (int ks = 0; ks < 4; ++ks) {
      bf16x8 af[4], bfr[4];
      int kb2 = (ks * 32 + kgrp * 8) * 2;
      for (int m = 0; m < 4; ++m) {
        int r = wr * 64 + m * 16 + lrow;
        af[m] = *(const bf16x8*)((const char*)xa + ((r * 256 + kb2) ^ ((r & 7) << 4)));
      }
      for (int n = 0; n < 4; ++n) {
        int r = wc * 64 + n * 16 + lrow;
        bfr[n] = *(const bf16x8*)((const char*)wb + ((r * 256 + kb2) ^ ((r & 7) << 4)));
      }
      for (int m = 0; m < 4; ++m)
        for (int n = 0; n < 4; ++n)
          acc[m][n] = __builtin_amdgcn_mfma_f32_16x16x32_bf16(af[m], bfr[n], acc[m][n], 0, 0, 0);
    }

    unsigned short* fv = feat + (size_t)v * N_NODES * OUTD;
    for (int m = 0; m < 4; ++m)
      for (int n = 0; n < 4; ++n) {
        int col = wc * 64 + n * 16 + lrow;
        for (int r4 = 0; r4 < 4; ++r4) {
          int row = n0 + wr * 64 + m * 16 + kgrp * 4 + r4;
          if (row < N_NODES) fv[(size_t)row * OUTD + col] = f2bf(acc[m][n][r4]);
        }
      }
  }
}

// ---------------- el/er: per (view, node, head) attention logit halves ------
__global__ __launch_bounds__(256) void elr_kernel(
    const unsigned short* __restrict__ feat,
    const float* __restrict__ al_s, const float* __restrict__ ar_s,
    const float* __restrict__ al_t, const float* __restrict__ ar_t,
    const float* __restrict__ al_p, const float* __restrict__ ar_p,
    float* __restrict__ el, float* __restrict__ er) {
  int idx = blockIdx.x * 256 + threadIdx.x;
  if (idx >= 3 * N_NODES * NH) return;
  int v = idx / (N_NODES * NH);
  int rem = idx - v * (N_NODES * NH);
  int n = rem >> 3, h = rem & 7;
  const float* al = (v == 0) ? al_s : ((v == 1) ? al_t : al_p);
  const float* ar = (v == 0) ? ar_s : ((v == 1) ? ar_t : ar_p);
  const unsigned short* fr = feat + (size_t)v * N_NODES * OUTD + (size_t)n * OUTD + h * NF;
  uint4 a = *(const uint4*)(fr);
  uint4 b = *(const uint4*)(fr + 8);
  float fv[16];
  fv[0] = bf2f_lo(a.x); fv[1] = bf2f_hi(a.x); fv[2] = bf2f_lo(a.y); fv[3] = bf2f_hi(a.y);
  fv[4] = bf2f_lo(a.z); fv[5] = bf2f_hi(a.z); fv[6] = bf2f_lo(a.w); fv[7] = bf2f_hi(a.w);
  fv[8] = bf2f_lo(b.x); fv[9] = bf2f_hi(b.x); fv[10] = bf2f_lo(b.y); fv[11] = bf2f_hi(b.y);
  fv[12] = bf2f_lo(b.z); fv[13] = bf2f_hi(b.z); fv[14] = bf2f_lo(b.w); fv[15] = bf2f_hi(b.w);
  float accl = 0.f, accr = 0.f;
#pragma unroll
  for (int f = 0; f < NF; ++f) {
    accl += fv[f] * al[h * NF + f];
    accr += fv[f] * ar[h * NF + f];
  }
  el[idx] = accl;
  er[idx] = accr;
}

// ---------------- CSR build: bucket-binned counting sort --------------------
// Pass 1: bin edges by dst>>10 into 49 bucket regions, packed (src<<16)|dst.
__global__ __launch_bounds__(256) void bin_kernel(
    const int* __restrict__ src_s, const int* __restrict__ dst_s,
    const int* __restrict__ src_t, const int* __restrict__ dst_t,
    const int* __restrict__ src_p, const int* __restrict__ dst_p,
    int* __restrict__ gtail, unsigned int* __restrict__ gbin) {
  const int v = blockIdx.y;
  const int* S = (v == 0) ? src_s : ((v == 1) ? src_t : src_p);
  const int* D = (v == 0) ? dst_s : ((v == 1) ? dst_t : dst_p);
  __shared__ int lhist[64], lbase[64];
  const int t = threadIdx.x;
  if (t < 64) lhist[t] = 0;
  __syncthreads();
  const int e0 = blockIdx.x * BIN_EPB + t * BIN_EPT;
  unsigned int pk[BIN_EPT];
  int bk[BIN_EPT], rk[BIN_EPT];
#pragma unroll
  for (int i = 0; i < BIN_EPT; ++i) {
    int e = e0 + i;
    if (e < NE) {
      unsigned int s = (unsigned int)S[e], d = (unsigned int)D[e];
      pk[i] = (s << 16) | d;
      bk[i] = (int)(d >> 10);
      rk[i] = atomicAdd(&lhist[bk[i]], 1);
    } else {
      bk[i] = -1;
    }
  }
  __syncthreads();
  if (t < 64) {
    int c = lhist[t];
    lbase[t] = (c > 0) ? atomicAdd(&gtail[v * 64 + t], c) : 0;
  }
  __syncthreads();
#pragma unroll
  for (int i = 0; i < BIN_EPT; ++i) {
    if (bk[i] >= 0) {
      int pos = lbase[bk[i]] + rk[i];
      if (pos < BCAP)
        gbin[((size_t)v * 64 + bk[i]) * BCAP + pos] = pk[i];
    }
  }
}

// Pass 2: per-node counts from binned edges (atomics stay in 4KB windows).
__global__ __launch_bounds__(256) void hist2_kernel(
    const int* __restrict__ gtail, const unsigned int* __restrict__ gbin,
    int* __restrict__ counts) {
  const int v = blockIdx.y;
  const int b = blockIdx.x / NSPLIT, q = blockIdx.x % NSPLIT;
  int cnt = gtail[v * 64 + b];
  if (cnt > BCAP) cnt = BCAP;
  const unsigned int* eb = gbin + ((size_t)v * 64 + b) * BCAP;
  int* cv = counts + v * N_NODES;
  const int lo = cnt * q / NSPLIT, hi = cnt * (q + 1) / NSPLIT;
  for (int e = lo + (int)threadIdx.x; e < hi; e += 256)
    atomicAdd(cv + (eb[e] & 0xffffu), 1);
}

// two-level scan: 150 parallel local scans -> chunk-prefix scan -> fixup
__global__ __launch_bounds__(1024) void scan1_kernel(
    const int* __restrict__ counts, int* __restrict__ linc, int* __restrict__ bsum) {
  const int b = blockIdx.x;          // 0..149
  const int v = b / NCHUNK, c = b % NCHUNK;
  const int t = threadIdx.x;
  const int i = c * 1024 + t;        // index within view
  int val = (i < N_NODES) ? counts[v * N_NODES + i] : 0;
  __shared__ int sh[1024];
  sh[t] = val;
  __syncthreads();
  for (int st = 1; st < 1024; st <<= 1) {
    int add = (t >= st) ? sh[t - st] : 0;
    __syncthreads();
    sh[t] += add;
    __syncthreads();
  }
  linc[b * 1024 + t] = sh[t];
  if (t == 1023) bsum[b] = sh[1023];
}

__global__ __launch_bounds__(256) void scan2_kernel(
    const int* __restrict__ bsum, int* __restrict__ cpref) {
  const int w = threadIdx.x >> 6, lane = threadIdx.x & 63;
  if (w >= 3) return;
  int val = (lane < NCHUNK) ? bsum[w * NCHUNK + lane] : 0;
  int incl = val;
  for (int st = 1; st < 64; st <<= 1) {
    int other = __shfl_up(incl, st, 64);
    if (lane >= st) incl += other;
  }
  if (lane < NCHUNK) cpref[w * NCHUNK + lane] = incl - val;  // exclusive
}

__global__ __launch_bounds__(1024) void scan3_kernel(
    const int* __restrict__ counts, const int* __restrict__ linc,
    const int* __restrict__ cpref, int* __restrict__ offs, int* __restrict__ cursor) {
  const int b = blockIdx.x;
  const int v = b / NCHUNK, c = b % NCHUNK;
  const int t = threadIdx.x;
  const int i = c * 1024 + t;
  if (c == 0 && t == 0) offs[v * NOFF] = 0;
  if (i < N_NODES) {
    int total = cpref[b] + linc[b * 1024 + t];
    offs[v * NOFF + i + 1] = total;
    cursor[v * N_NODES + i] = total - counts[v * N_NODES + i];
  }
}

// Pass 3: dst-local scatter; esrc writes land in ~70KB windows (L2-resident).
__global__ __launch_bounds__(256) void local_scatter_kernel(
    const int* __restrict__ gtail, const unsigned int* __restrict__ gbin,
    int* __restrict__ cursor, int* __restrict__ esrc) {
  const int v = blockIdx.y;
  const int b = blockIdx.x / NSPLIT, q = blockIdx.x % NSPLIT;
  int cnt = gtail[v * 64 + b];
  if (cnt > BCAP) cnt = BCAP;
  const unsigned int* eb = gbin + ((size_t)v * 64 + b) * BCAP;
  int* cur = cursor + v * N_NODES;
  int* ev = esrc + (size_t)v * NE;
  const int lo = cnt * q / NSPLIT, hi = cnt * (q + 1) / NSPLIT;
  for (int e = lo + (int)threadIdx.x; e < hi; e += 256) {
    unsigned int pk = eb[e];
    int d = (int)(pk & 0xffffu);
    int s = (int)(pk >> 16);
    int pos = atomicAdd(cur + d, 1);
    ev[pos] = s;
  }
}

// ---------------- GAT aggregation: one wave per (view, dst node) ------------
__global__ __launch_bounds__(256) void gat_kernel(
    const int* __restrict__ offs, const int* __restrict__ esrc,
    const float* __restrict__ el, const float* __restrict__ er,
    const unsigned short* __restrict__ feat,
    const float* __restrict__ b_s, const float* __restrict__ b_t,
    const float* __restrict__ b_p, float* __restrict__ views) {
  const int v = blockIdx.y;
  const int n = blockIdx.x * 4 + (threadIdx.x >> 6);
  const int lane = threadIdx.x & 63;
  const int g = lane >> 4;       // edge sub-slot 0..3
  const int q = lane & 15;       // feature chunk: covers f = q*8 .. q*8+7
  const int h = q >> 1;          // head of this lane's feature chunk
  const int* off_v = offs + v * NOFF;
  const int off0 = off_v[n];
  const int deg = off_v[n + 1] - off0;   // >= 1 (self loop)
  const int* es = esrc + (size_t)v * NE + off0;
  const float* el_v = el + (size_t)v * N_NODES * NH;
  const float er_h = er[((size_t)v * N_NODES + n) * NH + h];
  const unsigned short* featv = feat + (size_t)v * N_NODES * OUTD;

  float acc[8];
#pragma unroll
  for (int j = 0; j < 8; ++j) acc[j] = 0.f;
  float sm = 0.f;

  for (int base = 0; base < deg; base += 8) {
    int e0 = base + g, e1 = base + 4 + g;
    bool v0 = e0 < deg, v1 = e1 < deg;
    int s0 = es[v0 ? e0 : 0];
    int s1 = es[v1 ? e1 : 0];
    float val0 = el_v[s0 * NH + h] + er_h;
    float val1 = el_v[s1 * NH + h] + er_h;
    uint4 pk0 = *(const uint4*)(featv + s0 * OUTD + q * 8);
    uint4 pk1 = *(const uint4*)(featv + s1 * OUTD + q * 8);
    val0 = (val0 > 0.f) ? val0 : 0.2f * val0;
    val1 = (val1 > 0.f) ? val1 : 0.2f * val1;
    float aw0 = v0 ? __expf(val0) : 0.f;
    float aw1 = v1 ? __expf(val1) : 0.f;
    sm += aw0 + aw1;
    acc[0] += aw0 * bf2f_lo(pk0.x) + aw1 * bf2f_lo(pk1.x);
    acc[1] += aw0 * bf2f_hi(pk0.x) + aw1 * bf2f_hi(pk1.x);
    acc[2] += aw0 * bf2f_lo(pk0.y) + aw1 * bf2f_lo(pk1.y);
    acc[3] += aw0 * bf2f_hi(pk0.y) + aw1 * bf2f_hi(pk1.y);
    acc[4] += aw0 * bf2f_lo(pk0.z) + aw1 * bf2f_lo(pk1.z);
    acc[5] += aw0 * bf2f_hi(pk0.z) + aw1 * bf2f_hi(pk1.z);
    acc[6] += aw0 * bf2f_lo(pk0.w) + aw1 * bf2f_lo(pk1.w);
    acc[7] += aw0 * bf2f_hi(pk0.w) + aw1 * bf2f_hi(pk1.w);
  }

#pragma unroll
  for (int m = 16; m < 64; m <<= 1) {
    sm += __shfl_xor(sm, m, 64);
#pragma unroll
    for (int j = 0; j < 8; ++j) acc[j] += __shfl_xor(acc[j], m, 64);
  }

  if (g == 0) {
    const float inv = 1.0f / sm;
    const float* bv = (v == 0) ? b_s : ((v == 1) ? b_t : b_p);
    float r[8];
#pragma unroll
    for (int j = 0; j < 8; ++j) {
      float x = acc[j] * inv + bv[q * 8 + j];
      r[j] = (x > 0.f) ? x : 0.f;
    }
    float* dst = views + (size_t)v * N_NODES * OUTD + (size_t)n * OUTD + q * 8;
    *(float4*)(dst) = make_float4(r[0], r[1], r[2], r[3]);
    *(float4*)(dst + 4) = make_float4(r[4], r[5], r[6], r[7]);
  }
}

// ---- fused view-reduction: logits[v] = sum_n (V Wq^T + bq).(V Wk^T + bk),
//      dsum[v] = sum(V .* Wm)  — MFMA for the skinny GEMMs, fp32 for Wm dot.
__global__ __launch_bounds__(256) void viewred_kernel(
    const float* __restrict__ views, const float* __restrict__ Wq,
    const float* __restrict__ bq, const float* __restrict__ Wk,
    const float* __restrict__ bk, const float* __restrict__ Wm,
    float* __restrict__ logits, float* __restrict__ dsum) {
  __shared__ unsigned short vt[128 * 128];  // V tile bf16, XOR-swizzled
  __shared__ unsigned short wq[16 * 128];   // Wq bf16, XOR-swizzled
  __shared__ unsigned short wk[16 * 128];
  __shared__ float redq[4], redd[4];
  const int v = blockIdx.y;
  const int n0 = blockIdx.x * 128;
  const int t = threadIdx.x;
  const float* Vv = views + (size_t)v * N_NODES * OUTD;

  {
    int flat = t * 8;
    int r = flat >> 7, c = flat & 127;
    int byteoff = (r * 256 + c * 2) ^ ((r & 7) << 4);
    float4 qa = *(const float4*)(Wq + flat);
    float4 qb = *(const float4*)(Wq + flat + 4);
    u16x8 oq;
    oq[0] = f2bf(qa.x); oq[1] = f2bf(qa.y); oq[2] = f2bf(qa.z); oq[3] = f2bf(qa.w);
    oq[4] = f2bf(qb.x); oq[5] = f2bf(qb.y); oq[6] = f2bf(qb.z); oq[7] = f2bf(qb.w);
    *(u16x8*)((char*)wq + byteoff) = oq;
    float4 ka = *(const float4*)(Wk + flat);
    float4 kb = *(const float4*)(Wk + flat + 4);
    u16x8 ok;
    ok[0] = f2bf(ka.x); ok[1] = f2bf(ka.y); ok[2] = f2bf(ka.z); ok[3] = f2bf(ka.w);
    ok[4] = f2bf(kb.x); ok[5] = f2bf(kb.y); ok[6] = f2bf(kb.z); ok[7] = f2bf(kb.w);
    *(u16x8*)((char*)wk + byteoff) = ok;
  }

  float dp = 0.f;
  for (int i = 0; i < 8; ++i) {
    int flat = (i * 256 + t) * 8;
    int r = flat >> 7, c = flat & 127;
    int row = n0 + r;
    u16x8 o = (u16x8)0;
    if (row < N_NODES) {
      size_t goff = (size_t)row * OUTD + c;
      float4 a = *(const float4*)(Vv + goff);
      float4 b = *(const float4*)(Vv + goff + 4);
      float4 wa = *(const float4*)(Wm + goff);
      float4 wb2 = *(const float4*)(Wm + goff + 4);
      dp += a.x * wa.x + a.y * wa.y + a.z * wa.z + a.w * wa.w;
      dp += b.x * wb2.x + b.y * wb2.y + b.z * wb2.z + b.w * wb2.w;
      o[0] = f2bf(a.x); o[1] = f2bf(a.y); o[2] = f2bf(a.z); o[3] = f2bf(a.w);
      o[4] = f2bf(b.x); o[5] = f2bf(b.y); o[6] = f2bf(b.z); o[7] = f2bf(b.w);
    }
    int byteoff = (r * 256 + c * 2) ^ ((r & 7) << 4);
    *(u16x8*)((char*)vt + byteoff) = o;
  }
  __syncthreads();

  const int wave = t >> 6, lane = t & 63;
  const int lrow = lane & 15;
  const int kgrp = lane >> 4;
  const float bqv = bq[lrow];
  const float bkv = bk[lrow];
  float qk = 0.f;

  f32x4 accQ[2], accK[2];
  accQ[0] = (f32x4)0.f; accQ[1] = (f32x4)0.f;
  accK[0] = (f32x4)0.f; accK[1] = (f32x4)0.f;
  for (int ks = 0; ks < 4; ++ks) {
    int kb2 = (ks * 32 + kgrp * 8) * 2;
    int rb = lrow;
    bf16x8 bqf = *(const bf16x8*)((const char*)wq + ((rb * 256 + kb2) ^ ((rb & 7) << 4)));
    bf16x8 bkf = *(const bf16x8*)((const char*)wk + ((rb * 256 + kb2) ^ ((rb & 7) << 4)));
#pragma unroll
    for (int m = 0; m < 2; ++m) {
      int r = (wave * 2 + m) * 16 + lrow;
      bf16x8 af = *(const bf16x8*)((const char*)vt + ((r * 256 + kb2) ^ ((r & 7) << 4)));
      accQ[m] = __builtin_amdgcn_mfma_f32_16x16x32_bf16(af, bqf, accQ[m], 0, 0, 0);
      accK[m] = __builtin_amdgcn_mfma_f32_16x16x32_bf16(af, bkf, accK[m], 0, 0, 0);
    }
  }
#pragma unroll
  for (int m = 0; m < 2; ++m) {
#pragma unroll
    for (int j = 0; j < 4; ++j) {
      int row = n0 + (wave * 2 + m) * 16 + kgrp * 4 + j;
      if (row < N_NODES) qk += (accQ[m][j] + bqv) * (accK[m][j] + bkv);
    }
  }

#pragma unroll
  for (int m = 1; m < 64; m <<= 1) {
    qk += __shfl_xor(qk, m, 64);
    dp += __shfl_xor(dp, m, 64);
  }
  if (lane == 0) { redq[wave] = qk; redd[wave] = dp; }
  __syncthreads();
  if (t == 0) {
    atomicAdd(&logits[v], redq[0] + redq[1] + redq[2] + redq[3]);
    atomicAdd(&dsum[v], redd[0] + redd[1] + redd[2] + redd[3]);
  }
}

// ---------------- scalar chain: softmax + sigmoid gates ---------------------
__global__ void scalar_kernel(const float* __restrict__ logits,
                              const float* __restrict__ dsum,
                              const float* __restrict__ bm, float* __restrict__ gc) {
  if (threadIdx.x == 0 && blockIdx.x == 0) {
    const float scale = 1.0f / sqrtf((float)(NF * N_NODES));
    float l0 = logits[0] * scale, l1 = logits[1] * scale, l2 = logits[2] * scale;
    float mx = fmaxf(l0, fmaxf(l1, l2));
    float e0 = __expf(l0 - mx), e1 = __expf(l1 - mx), e2 = __expf(l2 - mx);
    float inv = 1.0f / (e0 + e1 + e2);
    float g0 = 0.8f * e0 * inv + 0.2f;
    float g1 = 0.8f * e1 * inv + 0.2f;
    float g2 = 0.8f * e2 * inv + 0.2f;
    float bmv = bm[0];
    float o0 = 1.0f / (1.0f + __expf(-(g0 * dsum[0] + bmv)));
    float o1 = 1.0f / (1.0f + __expf(-(g1 * dsum[1] + bmv)));
    float o2 = 1.0f / (1.0f + __expf(-(g2 * dsum[2] + bmv)));
    gc[0] = g0; gc[1] = g1; gc[2] = g2;
    gc[3] = o0 * g0; gc[4] = o1 * g1; gc[5] = o2 * g2;
  }
}

// ---------------- epilogue: mv + result -------------------------------------
__global__ __launch_bounds__(256) void final_kernel(
    const float* __restrict__ views, const float* __restrict__ gc,
    float* __restrict__ out) {
  const size_t NT = (size_t)N_NODES * OUTD;
  size_t base = ((size_t)blockIdx.x * 256 + threadIdx.x) * 4;
  if (base >= NT) return;
  float g0 = gc[0], g1 = gc[1], g2 = gc[2], c0 = gc[3], c1 = gc[4], c2 = gc[5];
  float4 a0 = *(const float4*)(views + base);
  float4 a1 = *(const float4*)(views + NT + base);
  float4 a2 = *(const float4*)(views + 2 * NT + base);
  float4 mv;
  mv.x = c0 * a0.x + c1 * a1.x + c2 * a2.x;
  mv.y = c0 * a0.y + c1 * a1.y + c2 * a2.y;
  mv.z = c0 * a0.z + c1 * a1.z + c2 * a2.z;
  mv.w = c0 * a0.w + c1 * a1.w + c2 * a2.w;
  *(float4*)(out + base) = mv;
  float4 r;
  r.x = 0.5f * (g0 * a0.x) + 0.5f * mv.x;
  r.y = 0.5f * (g0 * a0.y) + 0.5f * mv.y;
  r.z = 0.5f * (g0 * a0.z) + 0.5f * mv.z;
  r.w = 0.5f * (g0 * a0.w) + 0.5f * mv.w;
  *(float4*)(out + NT + base) = r;
  r.x = 0.5f * (g1 * a1.x) + 0.5f * mv.x;
  r.y = 0.5f * (g1 * a1.y) + 0.5f * mv.y;
  r.z = 0.5f * (g1 * a1.z) + 0.5f * mv.z;
  r.w = 0.5f * (g1 * a1.w) + 0.5f * mv.w;
  *(float4*)(out + 2 * NT + base) = r;
  r.x = 0.5f * (g2 * a2.x) + 0.5f * mv.x;
  r.y = 0.5f * (g2 * a2.y) + 0.5f * mv.y;
  r.z = 0.5f * (g2 * a2.z) + 0.5f * mv.z;
  r.w = 0.5f * (g2 * a2.w) + 0.5f * mv.w;
  *(float4*)(out + 3 * NT + base) = r;
}

extern "C" void kernel_launch(void* const* d_in, const int* in_sizes, int n_in,
                              void* d_out, int out_size, void* d_ws, size_t ws_size,
                              hipStream_t stream) {
  const float* x = (const float*)d_in[0];
  const int* src_s = (const int*)d_in[1];
  const int* dst_s = (const int*)d_in[2];
  const int* src_t = (const int*)d_in[3];
  const int* dst_t = (const int*)d_in[4];
  const int* src_p = (const int*)d_in[5];
  const int* dst_p = (const int*)d_in[6];
  const float* W_s = (const float*)d_in[7];
  const float* al_s = (const float*)d_in[8];
  const float* ar_s = (const float*)d_in[9];
  const float* b_s = (const float*)d_in[10];
  const float* W_t = (const float*)d_in[11];
  const float* al_t = (const float*)d_in[12];
  const float* ar_t = (const float*)d_in[13];
  const float* b_t = (const float*)d_in[14];
  const float* W_p = (const float*)d_in[15];
  const float* al_p = (const float*)d_in[16];
  const float* ar_p = (const float*)d_in[17];
  const float* b_p = (const float*)d_in[18];
  const float* Wq = (const float*)d_in[19];
  const float* bq = (const float*)d_in[20];
  const float* Wk = (const float*)d_in[21];
  const float* bk = (const float*)d_in[22];
  const float* Wm = (const float*)d_in[23];
  const float* bm = (const float*)d_in[24];
  float* out = (float*)d_out;

  char* ws = (char*)d_ws;
  unsigned short* feat = (unsigned short*)ws;
  float* el = (float*)(ws + 38400000);
  float* er = (float*)(ws + 43200000);
  float* views = (float*)(ws + 48000000);
  int* offs = (int*)(ws + 124800000);
  int* cursor = (int*)(ws + 125400016);
  int* esrc = (int*)(ws + 126000016);
  int* counts = (int*)(ws + 136200016);
  int* gtail = (int*)(ws + 136800016);     // 3*64 ints = 768 B
  float* scal = (float*)(ws + 136800784);  // logits[3], dsum[3], gc[6]

  // overlays inside the (not yet written) views buffer
  int* linc = (int*)(ws + 48000000);
  int* bsum = (int*)(ws + 48000000 + 614400);
  int* cpref = (int*)(ws + 48000000 + 616000);
  unsigned int* gbin = (unsigned int*)(ws + 49000000);  // 14,155,776 B

  // zero counts + gtail + scal in one shot
  hipMemsetAsync(counts, 0, 600000 + 768 + 48, stream);

  gemm_feat_kernel<<<dim3(391), dim3(256), 0, stream>>>(x, W_s, W_t, W_p, feat);
  elr_kernel<<<dim3((3 * N_NODES * NH + 255) / 256), dim3(256), 0, stream>>>(
      feat, al_s, ar_s, al_t, ar_t, al_p, ar_p, el, er);
  bin_kernel<<<dim3((NE + BIN_EPB - 1) / BIN_EPB, 3), dim3(256), 0, stream>>>(
      src_s, dst_s, src_t, dst_t, src_p, dst_p, gtail, gbin);
  hist2_kernel<<<dim3(NBUCK * NSPLIT, 3), dim3(256), 0, stream>>>(gtail, gbin, counts);
  scan1_kernel<<<dim3(NBLK), dim3(1024), 0, stream>>>(counts, linc, bsum);
  scan2_kernel<<<dim3(1), dim3(256), 0, stream>>>(bsum, cpref);
  scan3_kernel<<<dim3(NBLK), dim3(1024), 0, stream>>>(counts, linc, cpref, offs, cursor);
  local_scatter_kernel<<<dim3(NBUCK * NSPLIT, 3), dim3(256), 0, stream>>>(
      gtail, gbin, cursor, esrc);
  gat_kernel<<<dim3(12500, 3), dim3(256), 0, stream>>>(
      offs, esrc, el, er, feat, b_s, b_t, b_p, views);
  viewred_kernel<<<dim3(391, 3), dim3(256), 0, stream>>>(
      views, Wq, bq, Wk, bk, Wm, scal, scal + 3);
  scalar_kernel<<<dim3(1), dim3(64), 0, stream>>>(scal, scal + 3, bm, scal + 6);
  final_kernel<<<dim3(6250), dim3(256), 0, stream>>>(views, scal + 6, out);
}

// Round 5
// 445.944 us; speedup vs baseline: 2.5888x; 1.3943x over previous
//
#include <hip/hip_runtime.h>

// MVURE layer: 3x GATConv + view attention fusion.
// Workspace layout (~137 MB):
//   feat   bf16 [3][N][128]   @ 0          (38,400,000 B)
//   el     f32  [3][N][8]     @ 38,400,000 ( 4,800,000 B)
//   er     f32  [3][N][8]     @ 43,200,000 ( 4,800,000 B)
//   views  f32  [3][N][128]   @ 48,000,000 (76,800,000 B)
//     overlay (consumed before gat_kernel writes views):
//       gbin  u32 [3][64][20480] @ ws+49,000,000 (15,728,640 B)
//   offs   i32  [3][N+1]      @ 124,800,000 (600,016 B padded)
//   esrc   i32  [3][E]        @ 126,000,016 (10,200,000 B)
//   gtail  i32  [3][64]       @ 136,800,016 (768 B)
//   scal   f32  logits[3],d[3],gc[6] @ 136,800,784 (48 B)

#define N_NODES 50000
#define DIM 128
#define OUTD 128
#define NH 8
#define NF 16
#define NE 850000            // 800000 random + 50000 self loops
#define NOFF 50001
#define NBUCK 49             // dst>>10 buckets (1024-node windows)
#define BCAP 20480           // per-bucket capacity (mean 17347, huge margin)
#define BIN_EPT 8
#define BIN_EPB 2048         // 256 threads * 8 edges

typedef float f32x4 __attribute__((ext_vector_type(4)));
typedef __bf16 bf16x8 __attribute__((ext_vector_type(8)));
typedef unsigned short u16x8 __attribute__((ext_vector_type(8)));

static __device__ __forceinline__ float bf2f_lo(unsigned int u) {
  return __uint_as_float(u << 16);
}
static __device__ __forceinline__ float bf2f_hi(unsigned int u) {
  return __uint_as_float(u & 0xffff0000u);
}
static __device__ __forceinline__ unsigned short f2bf(float f) {
  unsigned int u = __float_as_uint(f);
  unsigned int r = (u + 0x7fffu + ((u >> 16) & 1u)) >> 16;
  return (unsigned short)r;
}

// ---------------- GEMM: feat_v = x @ W_v^T (bf16 MFMA, fp32 accum) ----------
__global__ __launch_bounds__(256) void gemm_feat_kernel(
    const float* __restrict__ x, const float* __restrict__ Ws,
    const float* __restrict__ Wt, const float* __restrict__ Wp,
    unsigned short* __restrict__ feat) {
  __shared__ unsigned short xa[128 * 128];  // [row][k] bf16, XOR-swizzled
  __shared__ unsigned short wb[128 * 128];  // [o][k]  bf16, XOR-swizzled
  const int t = threadIdx.x;
  const int n0 = blockIdx.x * 128;

  for (int i = 0; i < 16; ++i) {
    int flat = (i * 256 + t) * 4;
    int r = flat >> 7, c = flat & 127;
    float4 val = make_float4(0.f, 0.f, 0.f, 0.f);
    if (n0 + r < N_NODES) val = *(const float4*)(x + (size_t)(n0 + r) * DIM + c);
    int byteoff = (r * 256 + c * 2) ^ ((r & 7) << 4);
    unsigned short* p = (unsigned short*)((char*)xa + byteoff);
    p[0] = f2bf(val.x); p[1] = f2bf(val.y); p[2] = f2bf(val.z); p[3] = f2bf(val.w);
  }

  const int wave = t >> 6, lane = t & 63;
  const int wr = wave >> 1, wc = wave & 1;
  const int lrow = lane & 15;
  const int kgrp = lane >> 4;

  for (int v = 0; v < 3; ++v) {
    const float* W = (v == 0) ? Ws : ((v == 1) ? Wt : Wp);
    __syncthreads();
    for (int i = 0; i < 16; ++i) {
      int flat = (i * 256 + t) * 4;
      int r = flat >> 7, c = flat & 127;
      float4 val = *(const float4*)(W + r * DIM + c);
      int byteoff = (r * 256 + c * 2) ^ ((r & 7) << 4);
      unsigned short* p = (unsigned short*)((char*)wb + byteoff);
      p[0] = f2bf(val.x); p[1] = f2bf(val.y); p[2] = f2bf(val.z); p[3] = f2bf(val.w);
    }
    __syncthreads();

    f32x4 acc[4][4];
    for (int m = 0; m < 4; ++m)
      for (int n = 0; n < 4; ++n) acc[m][n] = (f32x4)0.f;

    for (int ks = 0; ks < 4; ++ks) {
      bf16x8 af[4], bfr[4];
      int kb2 = (ks * 32 + kgrp * 8) * 2;
      for (int m = 0; m < 4; ++m) {
        int r = wr * 64 + m * 16 + lrow;
        af[m] = *(const bf16x8*)((const char*)xa + ((r * 256 + kb2) ^ ((r & 7) << 4)));
      }
      for (int n = 0; n < 4; ++n) {
        int r = wc * 64 + n * 16 + lrow;
        bfr[n] = *(const bf16x8*)((const char*)wb + ((r * 256 + kb2) ^ ((r & 7) << 4)));
      }
      for (int m = 0; m < 4; ++m)
        for (int n = 0; n < 4; ++n)
          acc[m][n] = __builtin_amdgcn_mfma_f32_16x16x32_bf16(af[m], bfr[n], acc[m][n], 0, 0, 0);
    }

    unsigned short* fv = feat + (size_t)v * N_NODES * OUTD;
    for (int m = 0; m < 4; ++m)
      for (int n = 0; n < 4; ++n) {
        int col = wc * 64 + n * 16 + lrow;
        for (int r4 = 0; r4 < 4; ++r4) {
          int row = n0 + wr * 64 + m * 16 + kgrp * 4 + r4;
          if (row < N_NODES) fv[(size_t)row * OUTD + col] = f2bf(acc[m][n][r4]);
        }
      }
  }
}

// ---------------- el/er: per (view, node, head) attention logit halves ------
__global__ __launch_bounds__(256) void elr_kernel(
    const unsigned short* __restrict__ feat,
    const float* __restrict__ al_s, const float* __restrict__ ar_s,
    const float* __restrict__ al_t, const float* __restrict__ ar_t,
    const float* __restrict__ al_p, const float* __restrict__ ar_p,
    float* __restrict__ el, float* __restrict__ er) {
  int idx = blockIdx.x * 256 + threadIdx.x;
  if (idx >= 3 * N_NODES * NH) return;
  int v = idx / (N_NODES * NH);
  int rem = idx - v * (N_NODES * NH);
  int n = rem >> 3, h = rem & 7;
  const float* al = (v == 0) ? al_s : ((v == 1) ? al_t : al_p);
  const float* ar = (v == 0) ? ar_s : ((v == 1) ? ar_t : ar_p);
  const unsigned short* fr = feat + (size_t)v * N_NODES * OUTD + (size_t)n * OUTD + h * NF;
  uint4 a = *(const uint4*)(fr);
  uint4 b = *(const uint4*)(fr + 8);
  float fv[16];
  fv[0] = bf2f_lo(a.x); fv[1] = bf2f_hi(a.x); fv[2] = bf2f_lo(a.y); fv[3] = bf2f_hi(a.y);
  fv[4] = bf2f_lo(a.z); fv[5] = bf2f_hi(a.z); fv[6] = bf2f_lo(a.w); fv[7] = bf2f_hi(a.w);
  fv[8] = bf2f_lo(b.x); fv[9] = bf2f_hi(b.x); fv[10] = bf2f_lo(b.y); fv[11] = bf2f_hi(b.y);
  fv[12] = bf2f_lo(b.z); fv[13] = bf2f_hi(b.z); fv[14] = bf2f_lo(b.w); fv[15] = bf2f_hi(b.w);
  float accl = 0.f, accr = 0.f;
#pragma unroll
  for (int f = 0; f < NF; ++f) {
    accl += fv[f] * al[h * NF + f];
    accr += fv[f] * ar[h * NF + f];
  }
  el[idx] = accl;
  er[idx] = accr;
}

// ---------------- CSR build: bucket-binned LDS counting sort ----------------
// Pass 1: bin edges by dst>>10 into 49 bucket regions, packed (src<<16)|dst.
__global__ __launch_bounds__(256) void bin_kernel(
    const int* __restrict__ src_s, const int* __restrict__ dst_s,
    const int* __restrict__ src_t, const int* __restrict__ dst_t,
    const int* __restrict__ src_p, const int* __restrict__ dst_p,
    int* __restrict__ gtail, unsigned int* __restrict__ gbin) {
  const int v = blockIdx.y;
  const int* S = (v == 0) ? src_s : ((v == 1) ? src_t : src_p);
  const int* D = (v == 0) ? dst_s : ((v == 1) ? dst_t : dst_p);
  __shared__ int lhist[64], lbase[64];
  const int t = threadIdx.x;
  if (t < 64) lhist[t] = 0;
  __syncthreads();
  const int e0 = blockIdx.x * BIN_EPB + t * BIN_EPT;
  unsigned int pk[BIN_EPT];
  int bk[BIN_EPT], rk[BIN_EPT];
#pragma unroll
  for (int i = 0; i < BIN_EPT; ++i) {
    int e = e0 + i;
    if (e < NE) {
      unsigned int s = (unsigned int)S[e], d = (unsigned int)D[e];
      pk[i] = (s << 16) | d;
      bk[i] = (int)(d >> 10);
      rk[i] = atomicAdd(&lhist[bk[i]], 1);
    } else {
      bk[i] = -1;
    }
  }
  __syncthreads();
  if (t < 64) {
    int c = lhist[t];
    lbase[t] = (c > 0) ? atomicAdd(&gtail[v * 64 + t], c) : 0;
  }
  __syncthreads();
#pragma unroll
  for (int i = 0; i < BIN_EPT; ++i) {
    if (bk[i] >= 0) {
      int pos = lbase[bk[i]] + rk[i];
      if (pos < BCAP)
        gbin[((size_t)v * 64 + bk[i]) * BCAP + pos] = pk[i];
    }
  }
}

// Pass 2: one block per (view,bucket). LDS counting sort of <=20480 edges over
// 1024 dst nodes. Produces offs (coalesced) and esrc (coalesced) directly —
// no global atomics, no partial-line global writes, single-XCD locality.
__global__ __launch_bounds__(256) void bucket_sort_kernel(
    const int* __restrict__ gtail, const unsigned int* __restrict__ gbin,
    int* __restrict__ offs, int* __restrict__ esrc) {
  __shared__ int lhist[1024];          // per-node count -> exclusive base
  __shared__ int lcur[1024];           // running cursor for placement
  __shared__ int wsum[4];
  __shared__ int sh_bbase;
  __shared__ unsigned int sorted[BCAP];
  const int v = blockIdx.y;
  const int b = blockIdx.x;            // 0..NBUCK-1
  const int t = threadIdx.x;
  const int wave = t >> 6, lane = t & 63;

  int cnt = gtail[v * 64 + b];
  if (cnt > BCAP) cnt = BCAP;
  const unsigned int* eb = gbin + ((size_t)v * 64 + b) * BCAP;

  // bucket base: sum of previous buckets' counts (wave 0)
  if (t < 64) {
    int valb = (t < b) ? gtail[v * 64 + t] : 0;
#pragma unroll
    for (int m = 1; m < 64; m <<= 1) valb += __shfl_xor(valb, m, 64);
    if (t == 0) sh_bbase = valb;
  }
  // zero histogram
  lhist[t] = 0; lhist[t + 256] = 0; lhist[t + 512] = 0; lhist[t + 768] = 0;
  __syncthreads();

  // phase B: histogram via LDS atomics
  for (int e = t; e < cnt; e += 256)
    atomicAdd(&lhist[eb[e] & 1023u], 1);
  __syncthreads();

  // phase C: exclusive scan of 1024 counts (4 per thread)
  const int i0 = t * 4;
  int c0 = lhist[i0], c1 = lhist[i0 + 1], c2 = lhist[i0 + 2], c3 = lhist[i0 + 3];
  int s = c0 + c1 + c2 + c3;
  int incl = s;
#pragma unroll
  for (int st = 1; st < 64; st <<= 1) {
    int o = __shfl_up(incl, st, 64);
    if (lane >= st) incl += o;
  }
  if (lane == 63) wsum[wave] = incl;
  __syncthreads();
  if (t == 0) {
    int a = 0;
#pragma unroll
    for (int i = 0; i < 4; ++i) { int tmp = wsum[i]; wsum[i] = a; a += tmp; }
  }
  __syncthreads();
  const int base0 = wsum[wave] + (incl - s);
  lhist[i0] = base0;
  lhist[i0 + 1] = base0 + c0;
  lhist[i0 + 2] = base0 + c0 + c1;
  lhist[i0 + 3] = base0 + c0 + c1 + c2;
  lcur[i0] = base0;
  lcur[i0 + 1] = base0 + c0;
  lcur[i0 + 2] = base0 + c0 + c1;
  lcur[i0 + 3] = base0 + c0 + c1 + c2;

  // phase D: write offs (coalesced). offs[v][n+1] = bbase + inclusive_scan
  const int bbase = sh_bbase;
  if (b == 0 && t == 0) offs[v * NOFF] = 0;
  {
    int n = b * 1024 + i0;
    int in0 = base0 + c0, in1 = in0 + c1, in2 = in1 + c2, in3 = in2 + c3;
    if (n + 0 < N_NODES) offs[v * NOFF + n + 1] = bbase + in0;
    if (n + 1 < N_NODES) offs[v * NOFF + n + 2] = bbase + in1;
    if (n + 2 < N_NODES) offs[v * NOFF + n + 3] = bbase + in2;
    if (n + 3 < N_NODES) offs[v * NOFF + n + 4] = bbase + in3;
  }
  __syncthreads();

  // phase E: place srcs into sorted LDS positions
  for (int e = t; e < cnt; e += 256) {
    unsigned int pk = eb[e];
    int pos = atomicAdd(&lcur[pk & 1023u], 1);
    sorted[pos] = pk >> 16;
  }
  __syncthreads();

  // phase F: stream out coalesced
  int* ev = esrc + (size_t)v * NE + bbase;
  for (int e = t; e < cnt; e += 256) ev[e] = (int)sorted[e];
}

// ---------------- GAT aggregation: one wave per (view, dst node) ------------
__global__ __launch_bounds__(256) void gat_kernel(
    const int* __restrict__ offs, const int* __restrict__ esrc,
    const float* __restrict__ el, const float* __restrict__ er,
    const unsigned short* __restrict__ feat,
    const float* __restrict__ b_s, const float* __restrict__ b_t,
    const float* __restrict__ b_p, float* __restrict__ views) {
  const int v = blockIdx.y;
  const int n = blockIdx.x * 4 + (threadIdx.x >> 6);
  const int lane = threadIdx.x & 63;
  const int g = lane >> 4;       // edge sub-slot 0..3
  const int q = lane & 15;       // feature chunk: covers f = q*8 .. q*8+7
  const int h = q >> 1;          // head of this lane's feature chunk
  const int* off_v = offs + v * NOFF;
  const int off0 = off_v[n];
  const int deg = off_v[n + 1] - off0;   // >= 1 (self loop)
  const int* es = esrc + (size_t)v * NE + off0;
  const float* el_v = el + (size_t)v * N_NODES * NH;
  const float er_h = er[((size_t)v * N_NODES + n) * NH + h];
  const unsigned short* featv = feat + (size_t)v * N_NODES * OUTD;

  float acc[8];
#pragma unroll
  for (int j = 0; j < 8; ++j) acc[j] = 0.f;
  float sm = 0.f;

  for (int base = 0; base < deg; base += 8) {
    int e0 = base + g, e1 = base + 4 + g;
    bool v0 = e0 < deg, v1 = e1 < deg;
    int s0 = es[v0 ? e0 : 0];
    int s1 = es[v1 ? e1 : 0];
    float val0 = el_v[s0 * NH + h] + er_h;
    float val1 = el_v[s1 * NH + h] + er_h;
    uint4 pk0 = *(const uint4*)(featv + s0 * OUTD + q * 8);
    uint4 pk1 = *(const uint4*)(featv + s1 * OUTD + q * 8);
    val0 = (val0 > 0.f) ? val0 : 0.2f * val0;
    val1 = (val1 > 0.f) ? val1 : 0.2f * val1;
    float aw0 = v0 ? __expf(val0) : 0.f;
    float aw1 = v1 ? __expf(val1) : 0.f;
    sm += aw0 + aw1;
    acc[0] += aw0 * bf2f_lo(pk0.x) + aw1 * bf2f_lo(pk1.x);
    acc[1] += aw0 * bf2f_hi(pk0.x) + aw1 * bf2f_hi(pk1.x);
    acc[2] += aw0 * bf2f_lo(pk0.y) + aw1 * bf2f_lo(pk1.y);
    acc[3] += aw0 * bf2f_hi(pk0.y) + aw1 * bf2f_hi(pk1.y);
    acc[4] += aw0 * bf2f_lo(pk0.z) + aw1 * bf2f_lo(pk1.z);
    acc[5] += aw0 * bf2f_hi(pk0.z) + aw1 * bf2f_hi(pk1.z);
    acc[6] += aw0 * bf2f_lo(pk0.w) + aw1 * bf2f_lo(pk1.w);
    acc[7] += aw0 * bf2f_hi(pk0.w) + aw1 * bf2f_hi(pk1.w);
  }

#pragma unroll
  for (int m = 16; m < 64; m <<= 1) {
    sm += __shfl_xor(sm, m, 64);
#pragma unroll
    for (int j = 0; j < 8; ++j) acc[j] += __shfl_xor(acc[j], m, 64);
  }

  if (g == 0) {
    const float inv = 1.0f / sm;
    const float* bv = (v == 0) ? b_s : ((v == 1) ? b_t : b_p);
    float r[8];
#pragma unroll
    for (int j = 0; j < 8; ++j) {
      float x = acc[j] * inv + bv[q * 8 + j];
      r[j] = (x > 0.f) ? x : 0.f;
    }
    float* dst = views + (size_t)v * N_NODES * OUTD + (size_t)n * OUTD + q * 8;
    *(float4*)(dst) = make_float4(r[0], r[1], r[2], r[3]);
    *(float4*)(dst + 4) = make_float4(r[4], r[5], r[6], r[7]);
  }
}

// ---- fused view-reduction: logits[v] = sum_n (V Wq^T + bq).(V Wk^T + bk),
//      dsum[v] = sum(V .* Wm)  — MFMA for the skinny GEMMs, fp32 for Wm dot.
__global__ __launch_bounds__(256) void viewred_kernel(
    const float* __restrict__ views, const float* __restrict__ Wq,
    const float* __restrict__ bq, const float* __restrict__ Wk,
    const float* __restrict__ bk, const float* __restrict__ Wm,
    float* __restrict__ logits, float* __restrict__ dsum) {
  __shared__ unsigned short vt[128 * 128];  // V tile bf16, XOR-swizzled
  __shared__ unsigned short wq[16 * 128];   // Wq bf16, XOR-swizzled
  __shared__ unsigned short wk[16 * 128];
  __shared__ float redq[4], redd[4];
  const int v = blockIdx.y;
  const int n0 = blockIdx.x * 128;
  const int t = threadIdx.x;
  const float* Vv = views + (size_t)v * N_NODES * OUTD;

  {
    int flat = t * 8;
    int r = flat >> 7, c = flat & 127;
    int byteoff = (r * 256 + c * 2) ^ ((r & 7) << 4);
    float4 qa = *(const float4*)(Wq + flat);
    float4 qb = *(const float4*)(Wq + flat + 4);
    u16x8 oq;
    oq[0] = f2bf(qa.x); oq[1] = f2bf(qa.y); oq[2] = f2bf(qa.z); oq[3] = f2bf(qa.w);
    oq[4] = f2bf(qb.x); oq[5] = f2bf(qb.y); oq[6] = f2bf(qb.z); oq[7] = f2bf(qb.w);
    *(u16x8*)((char*)wq + byteoff) = oq;
    float4 ka = *(const float4*)(Wk + flat);
    float4 kb = *(const float4*)(Wk + flat + 4);
    u16x8 ok;
    ok[0] = f2bf(ka.x); ok[1] = f2bf(ka.y); ok[2] = f2bf(ka.z); ok[3] = f2bf(ka.w);
    ok[4] = f2bf(kb.x); ok[5] = f2bf(kb.y); ok[6] = f2bf(kb.z); ok[7] = f2bf(kb.w);
    *(u16x8*)((char*)wk + byteoff) = ok;
  }

  float dp = 0.f;
  for (int i = 0; i < 8; ++i) {
    int flat = (i * 256 + t) * 8;
    int r = flat >> 7, c = flat & 127;
    int row = n0 + r;
    u16x8 o = (u16x8)0;
    if (row < N_NODES) {
      size_t goff = (size_t)row * OUTD + c;
      float4 a = *(const float4*)(Vv + goff);
      float4 b = *(const float4*)(Vv + goff + 4);
      float4 wa = *(const float4*)(Wm + goff);
      float4 wb2 = *(const float4*)(Wm + goff + 4);
      dp += a.x * wa.x + a.y * wa.y + a.z * wa.z + a.w * wa.w;
      dp += b.x * wb2.x + b.y * wb2.y + b.z * wb2.z + b.w * wb2.w;
      o[0] = f2bf(a.x); o[1] = f2bf(a.y); o[2] = f2bf(a.z); o[3] = f2bf(a.w);
      o[4] = f2bf(b.x); o[5] = f2bf(b.y); o[6] = f2bf(b.z); o[7] = f2bf(b.w);
    }
    int byteoff = (r * 256 + c * 2) ^ ((r & 7) << 4);
    *(u16x8*)((char*)vt + byteoff) = o;
  }
  __syncthreads();

  const int wave = t >> 6, lane = t & 63;
  const int lrow = lane & 15;
  const int kgrp = lane >> 4;
  const float bqv = bq[lrow];
  const float bkv = bk[lrow];
  float qk = 0.f;

  f32x4 accQ[2], accK[2];
  accQ[0] = (f32x4)0.f; accQ[1] = (f32x4)0.f;
  accK[0] = (f32x4)0.f; accK[1] = (f32x4)0.f;
  for (int ks = 0; ks < 4; ++ks) {
    int kb2 = (ks * 32 + kgrp * 8) * 2;
    int rb = lrow;
    bf16x8 bqf = *(const bf16x8*)((const char*)wq + ((rb * 256 + kb2) ^ ((rb & 7) << 4)));
    bf16x8 bkf = *(const bf16x8*)((const char*)wk + ((rb * 256 + kb2) ^ ((rb & 7) << 4)));
#pragma unroll
    for (int m = 0; m < 2; ++m) {
      int r = (wave * 2 + m) * 16 + lrow;
      bf16x8 af = *(const bf16x8*)((const char*)vt + ((r * 256 + kb2) ^ ((r & 7) << 4)));
      accQ[m] = __builtin_amdgcn_mfma_f32_16x16x32_bf16(af, bqf, accQ[m], 0, 0, 0);
      accK[m] = __builtin_amdgcn_mfma_f32_16x16x32_bf16(af, bkf, accK[m], 0, 0, 0);
    }
  }
#pragma unroll
  for (int m = 0; m < 2; ++m) {
#pragma unroll
    for (int j = 0; j < 4; ++j) {
      int row = n0 + (wave * 2 + m) * 16 + kgrp * 4 + j;
      if (row < N_NODES) qk += (accQ[m][j] + bqv) * (accK[m][j] + bkv);
    }
  }

#pragma unroll
  for (int m = 1; m < 64; m <<= 1) {
    qk += __shfl_xor(qk, m, 64);
    dp += __shfl_xor(dp, m, 64);
  }
  if (lane == 0) { redq[wave] = qk; redd[wave] = dp; }
  __syncthreads();
  if (t == 0) {
    atomicAdd(&logits[v], redq[0] + redq[1] + redq[2] + redq[3]);
    atomicAdd(&dsum[v], redd[0] + redd[1] + redd[2] + redd[3]);
  }
}

// ---------------- scalar chain: softmax + sigmoid gates ---------------------
__global__ void scalar_kernel(const float* __restrict__ logits,
                              const float* __restrict__ dsum,
                              const float* __restrict__ bm, float* __restrict__ gc) {
  if (threadIdx.x == 0 && blockIdx.x == 0) {
    const float scale = 1.0f / sqrtf((float)(NF * N_NODES));
    float l0 = logits[0] * scale, l1 = logits[1] * scale, l2 = logits[2] * scale;
    float mx = fmaxf(l0, fmaxf(l1, l2));
    float e0 = __expf(l0 - mx), e1 = __expf(l1 - mx), e2 = __expf(l2 - mx);
    float inv = 1.0f / (e0 + e1 + e2);
    float g0 = 0.8f * e0 * inv + 0.2f;
    float g1 = 0.8f * e1 * inv + 0.2f;
    float g2 = 0.8f * e2 * inv + 0.2f;
    float bmv = bm[0];
    float o0 = 1.0f / (1.0f + __expf(-(g0 * dsum[0] + bmv)));
    float o1 = 1.0f / (1.0f + __expf(-(g1 * dsum[1] + bmv)));
    float o2 = 1.0f / (1.0f + __expf(-(g2 * dsum[2] + bmv)));
    gc[0] = g0; gc[1] = g1; gc[2] = g2;
    gc[3] = o0 * g0; gc[4] = o1 * g1; gc[5] = o2 * g2;
  }
}

// ---------------- epilogue: mv + result -------------------------------------
__global__ __launch_bounds__(256) void final_kernel(
    const float* __restrict__ views, const float* __restrict__ gc,
    float* __restrict__ out) {
  const size_t NT = (size_t)N_NODES * OUTD;
  size_t base = ((size_t)blockIdx.x * 256 + threadIdx.x) * 4;
  if (base >= NT) return;
  float g0 = gc[0], g1 = gc[1], g2 = gc[2], c0 = gc[3], c1 = gc[4], c2 = gc[5];
  float4 a0 = *(const float4*)(views + base);
  float4 a1 = *(const float4*)(views + NT + base);
  float4 a2 = *(const float4*)(views + 2 * NT + base);
  float4 mv;
  mv.x = c0 * a0.x + c1 * a1.x + c2 * a2.x;
  mv.y = c0 * a0.y + c1 * a1.y + c2 * a2.y;
  mv.z = c0 * a0.z + c1 * a1.z + c2 * a2.z;
  mv.w = c0 * a0.w + c1 * a1.w + c2 * a2.w;
  *(float4*)(out + base) = mv;
  float4 r;
  r.x = 0.5f * (g0 * a0.x) + 0.5f * mv.x;
  r.y = 0.5f * (g0 * a0.y) + 0.5f * mv.y;
  r.z = 0.5f * (g0 * a0.z) + 0.5f * mv.z;
  r.w = 0.5f * (g0 * a0.w) + 0.5f * mv.w;
  *(float4*)(out + NT + base) = r;
  r.x = 0.5f * (g1 * a1.x) + 0.5f * mv.x;
  r.y = 0.5f * (g1 * a1.y) + 0.5f * mv.y;
  r.z = 0.5f * (g1 * a1.z) + 0.5f * mv.z;
  r.w = 0.5f * (g1 * a1.w) + 0.5f * mv.w;
  *(float4*)(out + 2 * NT + base) = r;
  r.x = 0.5f * (g2 * a2.x) + 0.5f * mv.x;
  r.y = 0.5f * (g2 * a2.y) + 0.5f * mv.y;
  r.z = 0.5f * (g2 * a2.z) + 0.5f * mv.z;
  r.w = 0.5f * (g2 * a2.w) + 0.5f * mv.w;
  *(float4*)(out + 3 * NT + base) = r;
}

extern "C" void kernel_launch(void* const* d_in, const int* in_sizes, int n_in,
                              void* d_out, int out_size, void* d_ws, size_t ws_size,
                              hipStream_t stream) {
  const float* x = (const float*)d_in[0];
  const int* src_s = (const int*)d_in[1];
  const int* dst_s = (const int*)d_in[2];
  const int* src_t = (const int*)d_in[3];
  const int* dst_t = (const int*)d_in[4];
  const int* src_p = (const int*)d_in[5];
  const int* dst_p = (const int*)d_in[6];
  const float* W_s = (const float*)d_in[7];
  const float* al_s = (const float*)d_in[8];
  const float* ar_s = (const float*)d_in[9];
  const float* b_s = (const float*)d_in[10];
  const float* W_t = (const float*)d_in[11];
  const float* al_t = (const float*)d_in[12];
  const float* ar_t = (const float*)d_in[13];
  const float* b_t = (const float*)d_in[14];
  const float* W_p = (const float*)d_in[15];
  const float* al_p = (const float*)d_in[16];
  const float* ar_p = (const float*)d_in[17];
  const float* b_p = (const float*)d_in[18];
  const float* Wq = (const float*)d_in[19];
  const float* bq = (const float*)d_in[20];
  const float* Wk = (const float*)d_in[21];
  const float* bk = (const float*)d_in[22];
  const float* Wm = (const float*)d_in[23];
  const float* bm = (const float*)d_in[24];
  float* out = (float*)d_out;

  char* ws = (char*)d_ws;
  unsigned short* feat = (unsigned short*)ws;
  float* el = (float*)(ws + 38400000);
  float* er = (float*)(ws + 43200000);
  float* views = (float*)(ws + 48000000);
  int* offs = (int*)(ws + 124800000);
  int* esrc = (int*)(ws + 126000016);
  int* gtail = (int*)(ws + 136800016);     // 3*64 ints = 768 B
  float* scal = (float*)(ws + 136800784);  // logits[3], dsum[3], gc[6]

  // overlay inside the (not yet written) views buffer
  unsigned int* gbin = (unsigned int*)(ws + 49000000);  // 15,728,640 B

  hipMemsetAsync(gtail, 0, 768 + 48, stream);

  gemm_feat_kernel<<<dim3(391), dim3(256), 0, stream>>>(x, W_s, W_t, W_p, feat);
  elr_kernel<<<dim3((3 * N_NODES * NH + 255) / 256), dim3(256), 0, stream>>>(
      feat, al_s, ar_s, al_t, ar_t, al_p, ar_p, el, er);
  bin_kernel<<<dim3((NE + BIN_EPB - 1) / BIN_EPB, 3), dim3(256), 0, stream>>>(
      src_s, dst_s, src_t, dst_t, src_p, dst_p, gtail, gbin);
  bucket_sort_kernel<<<dim3(NBUCK, 3), dim3(256), 0, stream>>>(
      gtail, gbin, offs, esrc);
  gat_kernel<<<dim3(12500, 3), dim3(256), 0, stream>>>(
      offs, esrc, el, er, feat, b_s, b_t, b_p, views);
  viewred_kernel<<<dim3(391, 3), dim3(256), 0, stream>>>(
      views, Wq, bq, Wk, bk, Wm, scal, scal + 3);
  scalar_kernel<<<dim3(1), dim3(64), 0, stream>>>(scal, scal + 3, bm, scal + 6);
  final_kernel<<<dim3(6250), dim3(256), 0, stream>>>(views, scal + 6, out);
}

// Round 6
// 418.947 us; speedup vs baseline: 2.7556x; 1.0644x over previous
//
#include <hip/hip_runtime.h>

// MVURE layer: 3x GATConv + view attention fusion.
// Workspace layout (~137 MB):
//   feat   bf16 [3][N][128]   @ 0          (38,400,000 B)
//   el     f32  [3][N][8]     @ 38,400,000 ( 4,800,000 B)
//   er     f32  [3][N][8]     @ 43,200,000 ( 4,800,000 B)
//   views  f32  [3][N][128]   @ 48,000,000 (76,800,000 B)
//     overlay (consumed before gat_kernel writes views):
//       gbin  u32 [3][64][20480] @ ws+49,000,000 (15,728,640 B)
//   offs   i32  [3][N+1]      @ 124,800,000 (600,016 B padded)
//   esrc   i32  [3][E]        @ 126,000,016 (10,200,000 B)
//   gtail  i32  [3][64]       @ 136,800,016 (768 B)
//   scal   f32  logits[3],d[3],gc[6] @ 136,800,784 (48 B)

#define N_NODES 50000
#define DIM 128
#define OUTD 128
#define NH 8
#define NF 16
#define NE 850000            // 800000 random + 50000 self loops
#define NOFF 50001
#define NBUCK 49             // dst>>10 buckets (1024-node windows)
#define BCAP 20480           // per-bucket capacity (mean 17347, huge margin)
#define BIN_EPT 8
#define BIN_EPB 2048         // 256 threads * 8 edges

typedef float f32x4 __attribute__((ext_vector_type(4)));
typedef float f32x2 __attribute__((ext_vector_type(2)));
typedef __bf16 bf16x8 __attribute__((ext_vector_type(8)));
typedef unsigned short u16x8 __attribute__((ext_vector_type(8)));

static __device__ __forceinline__ float bf2f_lo(unsigned int u) {
  return __uint_as_float(u << 16);
}
static __device__ __forceinline__ float bf2f_hi(unsigned int u) {
  return __uint_as_float(u & 0xffff0000u);
}
static __device__ __forceinline__ f32x2 up2(unsigned int u) {
  f32x2 r;
  r.x = __uint_as_float(u << 16);
  r.y = __uint_as_float(u & 0xffff0000u);
  return r;
}
static __device__ __forceinline__ unsigned short f2bf(float f) {
  unsigned int u = __float_as_uint(f);
  unsigned int r = (u + 0x7fffu + ((u >> 16) & 1u)) >> 16;
  return (unsigned short)r;
}

// ---------------- GEMM: feat_v = x @ W_v^T (bf16 MFMA, fp32 accum) ----------
__global__ __launch_bounds__(256) void gemm_feat_kernel(
    const float* __restrict__ x, const float* __restrict__ Ws,
    const float* __restrict__ Wt, const float* __restrict__ Wp,
    unsigned short* __restrict__ feat) {
  __shared__ unsigned short xa[128 * 128];  // [row][k] bf16, XOR-swizzled
  __shared__ unsigned short wb[128 * 128];  // [o][k]  bf16, XOR-swizzled
  const int t = threadIdx.x;
  const int n0 = blockIdx.x * 128;

  for (int i = 0; i < 16; ++i) {
    int flat = (i * 256 + t) * 4;
    int r = flat >> 7, c = flat & 127;
    float4 val = make_float4(0.f, 0.f, 0.f, 0.f);
    if (n0 + r < N_NODES) val = *(const float4*)(x + (size_t)(n0 + r) * DIM + c);
    int byteoff = (r * 256 + c * 2) ^ ((r & 7) << 4);
    unsigned short* p = (unsigned short*)((char*)xa + byteoff);
    p[0] = f2bf(val.x); p[1] = f2bf(val.y); p[2] = f2bf(val.z); p[3] = f2bf(val.w);
  }

  const int wave = t >> 6, lane = t & 63;
  const int wr = wave >> 1, wc = wave & 1;
  const int lrow = lane & 15;
  const int kgrp = lane >> 4;

  for (int v = 0; v < 3; ++v) {
    const float* W = (v == 0) ? Ws : ((v == 1) ? Wt : Wp);
    __syncthreads();
    for (int i = 0; i < 16; ++i) {
      int flat = (i * 256 + t) * 4;
      int r = flat >> 7, c = flat & 127;
      float4 val = *(const float4*)(W + r * DIM + c);
      int byteoff = (r * 256 + c * 2) ^ ((r & 7) << 4);
      unsigned short* p = (unsigned short*)((char*)wb + byteoff);
      p[0] = f2bf(val.x); p[1] = f2bf(val.y); p[2] = f2bf(val.z); p[3] = f2bf(val.w);
    }
    __syncthreads();

    f32x4 acc[4][4];
    for (int m = 0; m < 4; ++m)
      for (int n = 0; n < 4; ++n) acc[m][n] = (f32x4)0.f;

    for (int ks = 0; ks < 4; ++ks) {
      bf16x8 af[4], bfr[4];
      int kb2 = (ks * 32 + kgrp * 8) * 2;
      for (int m = 0; m < 4; ++m) {
        int r = wr * 64 + m * 16 + lrow;
        af[m] = *(const bf16x8*)((const char*)xa + ((r * 256 + kb2) ^ ((r & 7) << 4)));
      }
      for (int n = 0; n < 4; ++n) {
        int r = wc * 64 + n * 16 + lrow;
        bfr[n] = *(const bf16x8*)((const char*)wb + ((r * 256 + kb2) ^ ((r & 7) << 4)));
      }
      for (int m = 0; m < 4; ++m)
        for (int n = 0; n < 4; ++n)
          acc[m][n] = __builtin_amdgcn_mfma_f32_16x16x32_bf16(af[m], bfr[n], acc[m][n], 0, 0, 0);
    }

    unsigned short* fv = feat + (size_t)v * N_NODES * OUTD;
    for (int m = 0; m < 4; ++m)
      for (int n = 0; n < 4; ++n) {
        int col = wc * 64 + n * 16 + lrow;
        for (int r4 = 0; r4 < 4; ++r4) {
          int row = n0 + wr * 64 + m * 16 + kgrp * 4 + r4;
          if (row < N_NODES) fv[(size_t)row * OUTD + col] = f2bf(acc[m][n][r4]);
        }
      }
  }
}

// ---------------- el/er: per (view, node, head) attention logit halves ------
__global__ __launch_bounds__(256) void elr_kernel(
    const unsigned short* __restrict__ feat,
    const float* __restrict__ al_s, const float* __restrict__ ar_s,
    const float* __restrict__ al_t, const float* __restrict__ ar_t,
    const float* __restrict__ al_p, const float* __restrict__ ar_p,
    float* __restrict__ el, float* __restrict__ er) {
  int idx = blockIdx.x * 256 + threadIdx.x;
  if (idx >= 3 * N_NODES * NH) return;
  int v = idx / (N_NODES * NH);
  int rem = idx - v * (N_NODES * NH);
  int n = rem >> 3, h = rem & 7;
  const float* al = (v == 0) ? al_s : ((v == 1) ? al_t : al_p);
  const float* ar = (v == 0) ? ar_s : ((v == 1) ? ar_t : ar_p);
  const unsigned short* fr = feat + (size_t)v * N_NODES * OUTD + (size_t)n * OUTD + h * NF;
  uint4 a = *(const uint4*)(fr);
  uint4 b = *(const uint4*)(fr + 8);
  float fv[16];
  fv[0] = bf2f_lo(a.x); fv[1] = bf2f_hi(a.x); fv[2] = bf2f_lo(a.y); fv[3] = bf2f_hi(a.y);
  fv[4] = bf2f_lo(a.z); fv[5] = bf2f_hi(a.z); fv[6] = bf2f_lo(a.w); fv[7] = bf2f_hi(a.w);
  fv[8] = bf2f_lo(b.x); fv[9] = bf2f_hi(b.x); fv[10] = bf2f_lo(b.y); fv[11] = bf2f_hi(b.y);
  fv[12] = bf2f_lo(b.z); fv[13] = bf2f_hi(b.z); fv[14] = bf2f_lo(b.w); fv[15] = bf2f_hi(b.w);
  float accl = 0.f, accr = 0.f;
#pragma unroll
  for (int f = 0; f < NF; ++f) {
    accl += fv[f] * al[h * NF + f];
    accr += fv[f] * ar[h * NF + f];
  }
  el[idx] = accl;
  er[idx] = accr;
}

// ---------------- CSR build: bucket-binned LDS counting sort ----------------
// Pass 1: bin edges by dst>>10 into 49 bucket regions, packed (src<<16)|dst.
// Per-wave histograms cut LDS-atomic serialization 4x.
__global__ __launch_bounds__(256) void bin_kernel(
    const int* __restrict__ src_s, const int* __restrict__ dst_s,
    const int* __restrict__ src_t, const int* __restrict__ dst_t,
    const int* __restrict__ src_p, const int* __restrict__ dst_p,
    int* __restrict__ gtail, unsigned int* __restrict__ gbin) {
  const int v = blockIdx.y;
  const int* S = (v == 0) ? src_s : ((v == 1) ? src_t : src_p);
  const int* D = (v == 0) ? dst_s : ((v == 1) ? dst_t : dst_p);
  __shared__ int lhist[4][64], lbase[4][64];
  const int t = threadIdx.x;
  const int wave = t >> 6;
  ((int*)lhist)[t] = 0;
  __syncthreads();
  const int e0 = blockIdx.x * BIN_EPB + t * BIN_EPT;
  unsigned int pk[BIN_EPT];
  int bk[BIN_EPT], rk[BIN_EPT];
#pragma unroll
  for (int i = 0; i < BIN_EPT; ++i) {
    int e = e0 + i;
    if (e < NE) {
      unsigned int s = (unsigned int)S[e], d = (unsigned int)D[e];
      pk[i] = (s << 16) | d;
      bk[i] = (int)(d >> 10);
      rk[i] = atomicAdd(&lhist[wave][bk[i]], 1);
    } else {
      bk[i] = -1;
    }
  }
  __syncthreads();
  if (t < 64) {
    int c0 = lhist[0][t], c1 = lhist[1][t], c2 = lhist[2][t], c3 = lhist[3][t];
    int tot = c0 + c1 + c2 + c3;
    int gb = (tot > 0) ? atomicAdd(&gtail[v * 64 + t], tot) : 0;
    lbase[0][t] = gb;
    lbase[1][t] = gb + c0;
    lbase[2][t] = gb + c0 + c1;
    lbase[3][t] = gb + c0 + c1 + c2;
  }
  __syncthreads();
#pragma unroll
  for (int i = 0; i < BIN_EPT; ++i) {
    if (bk[i] >= 0) {
      int pos = lbase[wave][bk[i]] + rk[i];
      if (pos < BCAP)
        gbin[((size_t)v * 64 + bk[i]) * BCAP + pos] = pk[i];
    }
  }
}

// Pass 2: one 1024-thread block per (view,bucket). LDS counting sort of
// <=20480 edges over 1024 dst nodes. Produces offs + esrc coalesced.
__global__ __launch_bounds__(1024) void bucket_sort_kernel(
    const int* __restrict__ gtail, const unsigned int* __restrict__ gbin,
    int* __restrict__ offs, int* __restrict__ esrc) {
  __shared__ int lcur[1024];
  __shared__ int wsum[16];
  __shared__ int sh_bbase;
  __shared__ unsigned int sorted[BCAP];
  __shared__ int lhist[1024];
  const int v = blockIdx.y;
  const int b = blockIdx.x;            // 0..NBUCK-1
  const int t = threadIdx.x;
  const int wave = t >> 6, lane = t & 63;

  int cnt = gtail[v * 64 + b];
  if (cnt > BCAP) cnt = BCAP;
  const unsigned int* eb = gbin + ((size_t)v * 64 + b) * BCAP;

  // bucket base: sum of previous buckets' counts (wave 0)
  if (t < 64) {
    int valb = (t < b) ? gtail[v * 64 + t] : 0;
#pragma unroll
    for (int m = 1; m < 64; m <<= 1) valb += __shfl_xor(valb, m, 64);
    if (t == 0) sh_bbase = valb;
  }
  lhist[t] = 0;
  __syncthreads();

  // phase B: histogram via LDS atomics
  for (int e = t; e < cnt; e += 1024)
    atomicAdd(&lhist[eb[e] & 1023u], 1);
  __syncthreads();

  // phase C: exclusive scan of 1024 counts (1 per thread)
  int val = lhist[t];
  int incl = val;
#pragma unroll
  for (int st = 1; st < 64; st <<= 1) {
    int o = __shfl_up(incl, st, 64);
    if (lane >= st) incl += o;
  }
  if (lane == 63) wsum[wave] = incl;
  __syncthreads();
  if (t < 64) {
    int wv = (lane < 16) ? wsum[lane] : 0;
    int winc = wv;
#pragma unroll
    for (int st = 1; st < 16; st <<= 1) {
      int o = __shfl_up(winc, st, 64);
      if (lane >= st) winc += o;
    }
    if (lane < 16) wsum[lane] = winc - wv;  // exclusive wave base
  }
  __syncthreads();
  const int base = wsum[wave] + incl - val;  // exclusive per-node base
  lcur[t] = base;

  // phase D: write offs (coalesced)
  const int bbase = sh_bbase;
  if (b == 0 && t == 0) offs[v * NOFF] = 0;
  {
    int n = b * 1024 + t;
    if (n < N_NODES) offs[v * NOFF + n + 1] = bbase + base + val;
  }
  __syncthreads();

  // phase E: place srcs into sorted LDS positions
  for (int e = t; e < cnt; e += 1024) {
    unsigned int pk = eb[e];
    int pos = atomicAdd(&lcur[pk & 1023u], 1);
    sorted[pos] = pk >> 16;
  }
  __syncthreads();

  // phase F: stream out coalesced
  int* ev = esrc + (size_t)v * NE + bbase;
  for (int e = t; e < cnt; e += 1024) ev[e] = (int)sorted[e];
}

// ---------------- GAT aggregation: one wave per (view, dst node) ------------
// Software-pipelined: prefetch next 8-edge chunk while computing current.
__global__ __launch_bounds__(256) void gat_kernel(
    const int* __restrict__ offs, const int* __restrict__ esrc,
    const float* __restrict__ el, const float* __restrict__ er,
    const unsigned short* __restrict__ feat,
    const float* __restrict__ b_s, const float* __restrict__ b_t,
    const float* __restrict__ b_p, float* __restrict__ views) {
  const int v = blockIdx.y;
  const int n = blockIdx.x * 4 + (threadIdx.x >> 6);
  const int lane = threadIdx.x & 63;
  const int g = lane >> 4;       // edge sub-slot 0..3
  const int q = lane & 15;       // feature chunk: covers f = q*8 .. q*8+7
  const int h = q >> 1;          // head of this lane's feature chunk
  const int* off_v = offs + v * NOFF;
  const int off0 = off_v[n];
  const int deg = off_v[n + 1] - off0;   // >= 1 (self loop)
  const int* es = esrc + (size_t)v * NE + off0;
  const float* el_v = el + (size_t)v * N_NODES * NH;
  const float er_h = er[((size_t)v * N_NODES + n) * NH + h];
  const unsigned short* featv = feat + (size_t)v * N_NODES * OUTD;

  f32x2 acc2[4];
#pragma unroll
  for (int j = 0; j < 4; ++j) acc2[j] = (f32x2)0.f;
  float sm = 0.f;

  // prologue: load chunk 0
  int e0 = g, e1 = 4 + g;
  bool v0 = e0 < deg, v1 = e1 < deg;
  int s0 = es[v0 ? e0 : 0];
  int s1 = es[v1 ? e1 : 0];
  float l0 = el_v[s0 * NH + h];
  float l1 = el_v[s1 * NH + h];
  uint4 pk0 = *(const uint4*)(featv + (size_t)s0 * OUTD + q * 8);
  uint4 pk1 = *(const uint4*)(featv + (size_t)s1 * OUTD + q * 8);

  for (int base = 0; base < deg; base += 8) {
    bool cv0 = v0, cv1 = v1;
    float cl0 = l0, cl1 = l1;
    uint4 cp0 = pk0, cp1 = pk1;
    int nb = base + 8;
    if (nb < deg) {  // prefetch next chunk
      e0 = nb + g; e1 = nb + 4 + g;
      v0 = e0 < deg; v1 = e1 < deg;
      s0 = es[v0 ? e0 : 0];
      s1 = es[v1 ? e1 : 0];
      l0 = el_v[s0 * NH + h];
      l1 = el_v[s1 * NH + h];
      pk0 = *(const uint4*)(featv + (size_t)s0 * OUTD + q * 8);
      pk1 = *(const uint4*)(featv + (size_t)s1 * OUTD + q * 8);
    }
    float val0 = cl0 + er_h;
    float val1 = cl1 + er_h;
    val0 = fmaxf(val0, 0.2f * val0);   // leaky_relu(0.2)
    val1 = fmaxf(val1, 0.2f * val1);
    float aw0 = cv0 ? __expf(val0) : 0.f;
    float aw1 = cv1 ? __expf(val1) : 0.f;
    sm += aw0 + aw1;
    acc2[0] += aw0 * up2(cp0.x) + aw1 * up2(cp1.x);
    acc2[1] += aw0 * up2(cp0.y) + aw1 * up2(cp1.y);
    acc2[2] += aw0 * up2(cp0.z) + aw1 * up2(cp1.z);
    acc2[3] += aw0 * up2(cp0.w) + aw1 * up2(cp1.w);
  }

  // reduce over the 4 edge-groups (lanes differing in bits 4,5)
#pragma unroll
  for (int m = 16; m < 64; m <<= 1) {
    sm += __shfl_xor(sm, m, 64);
#pragma unroll
    for (int j = 0; j < 4; ++j) {
      acc2[j].x += __shfl_xor(acc2[j].x, m, 64);
      acc2[j].y += __shfl_xor(acc2[j].y, m, 64);
    }
  }

  if (g == 0) {
    const float inv = 1.0f / sm;
    const float* bv = (v == 0) ? b_s : ((v == 1) ? b_t : b_p);
    float r[8];
#pragma unroll
    for (int j = 0; j < 4; ++j) {
      float x0 = acc2[j].x * inv + bv[q * 8 + 2 * j];
      float x1 = acc2[j].y * inv + bv[q * 8 + 2 * j + 1];
      r[2 * j] = (x0 > 0.f) ? x0 : 0.f;
      r[2 * j + 1] = (x1 > 0.f) ? x1 : 0.f;
    }
    float* dst = views + (size_t)v * N_NODES * OUTD + (size_t)n * OUTD + q * 8;
    *(float4*)(dst) = make_float4(r[0], r[1], r[2], r[3]);
    *(float4*)(dst + 4) = make_float4(r[4], r[5], r[6], r[7]);
  }
}

// ---- fused view-reduction: logits[v] = sum_n (V Wq^T + bq).(V Wk^T + bk),
//      dsum[v] = sum(V .* Wm). All 3 views per block -> Wm tile fetched once.
__global__ __launch_bounds__(256) void viewred_kernel(
    const float* __restrict__ views, const float* __restrict__ Wq,
    const float* __restrict__ bq, const float* __restrict__ Wk,
    const float* __restrict__ bk, const float* __restrict__ Wm,
    float* __restrict__ logits, float* __restrict__ dsum) {
  __shared__ unsigned short vt[128 * 128];  // V tile bf16, XOR-swizzled
  __shared__ unsigned short wq[16 * 128];   // Wq bf16, XOR-swizzled
  __shared__ unsigned short wk[16 * 128];
  __shared__ float redq[4], redd[4];
  const int n0 = blockIdx.x * 128;
  const int t = threadIdx.x;
  const int wave = t >> 6, lane = t & 63;
  const int lrow = lane & 15;
  const int kgrp = lane >> 4;

  {
    int flat = t * 8;
    int r = flat >> 7, c = flat & 127;
    int byteoff = (r * 256 + c * 2) ^ ((r & 7) << 4);
    float4 qa = *(const float4*)(Wq + flat);
    float4 qb = *(const float4*)(Wq + flat + 4);
    u16x8 oq;
    oq[0] = f2bf(qa.x); oq[1] = f2bf(qa.y); oq[2] = f2bf(qa.z); oq[3] = f2bf(qa.w);
    oq[4] = f2bf(qb.x); oq[5] = f2bf(qb.y); oq[6] = f2bf(qb.z); oq[7] = f2bf(qb.w);
    *(u16x8*)((char*)wq + byteoff) = oq;
    float4 ka = *(const float4*)(Wk + flat);
    float4 kb = *(const float4*)(Wk + flat + 4);
    u16x8 ok;
    ok[0] = f2bf(ka.x); ok[1] = f2bf(ka.y); ok[2] = f2bf(ka.z); ok[3] = f2bf(ka.w);
    ok[4] = f2bf(kb.x); ok[5] = f2bf(kb.y); ok[6] = f2bf(kb.z); ok[7] = f2bf(kb.w);
    *(u16x8*)((char*)wk + byteoff) = ok;
  }

  const float bqv = bq[lrow];
  const float bkv = bk[lrow];

  for (int v = 0; v < 3; ++v) {
    const float* Vv = views + (size_t)v * N_NODES * OUTD;
    float dp = 0.f;
    for (int i = 0; i < 8; ++i) {
      int flat = (i * 256 + t) * 8;
      int r = flat >> 7, c = flat & 127;
      int row = n0 + r;
      u16x8 o = (u16x8)0;
      if (row < N_NODES) {
        size_t goff = (size_t)row * OUTD + c;
        float4 a = *(const float4*)(Vv + goff);
        float4 b = *(const float4*)(Vv + goff + 4);
        float4 wa = *(const float4*)(Wm + goff);
        float4 wb2 = *(const float4*)(Wm + goff + 4);
        dp += a.x * wa.x + a.y * wa.y + a.z * wa.z + a.w * wa.w;
        dp += b.x * wb2.x + b.y * wb2.y + b.z * wb2.z + b.w * wb2.w;
        o[0] = f2bf(a.x); o[1] = f2bf(a.y); o[2] = f2bf(a.z); o[3] = f2bf(a.w);
        o[4] = f2bf(b.x); o[5] = f2bf(b.y); o[6] = f2bf(b.z); o[7] = f2bf(b.w);
      }
      int byteoff = (r * 256 + c * 2) ^ ((r & 7) << 4);
      *(u16x8*)((char*)vt + byteoff) = o;
    }
    __syncthreads();

    float qk = 0.f;
    f32x4 accQ[2], accK[2];
    accQ[0] = (f32x4)0.f; accQ[1] = (f32x4)0.f;
    accK[0] = (f32x4)0.f; accK[1] = (f32x4)0.f;
    for (int ks = 0; ks < 4; ++ks) {
      int kb2 = (ks * 32 + kgrp * 8) * 2;
      int rb = lrow;
      bf16x8 bqf = *(const bf16x8*)((const char*)wq + ((rb * 256 + kb2) ^ ((rb & 7) << 4)));
      bf16x8 bkf = *(const bf16x8*)((const char*)wk + ((rb * 256 + kb2) ^ ((rb & 7) << 4)));
#pragma unroll
      for (int m = 0; m < 2; ++m) {
        int r = (wave * 2 + m) * 16 + lrow;
        bf16x8 af = *(const bf16x8*)((const char*)vt + ((r * 256 + kb2) ^ ((r & 7) << 4)));
        accQ[m] = __builtin_amdgcn_mfma_f32_16x16x32_bf16(af, bqf, accQ[m], 0, 0, 0);
        accK[m] = __builtin_amdgcn_mfma_f32_16x16x32_bf16(af, bkf, accK[m], 0, 0, 0);
      }
    }
#pragma unroll
    for (int m = 0; m < 2; ++m) {
#pragma unroll
      for (int j = 0; j < 4; ++j) {
        int row = n0 + (wave * 2 + m) * 16 + kgrp * 4 + j;
        if (row < N_NODES) qk += (accQ[m][j] + bqv) * (accK[m][j] + bkv);
      }
    }

#pragma unroll
    for (int m = 1; m < 64; m <<= 1) {
      qk += __shfl_xor(qk, m, 64);
      dp += __shfl_xor(dp, m, 64);
    }
    if (lane == 0) { redq[wave] = qk; redd[wave] = dp; }
    __syncthreads();
    if (t == 0) {
      atomicAdd(&logits[v], redq[0] + redq[1] + redq[2] + redq[3]);
      atomicAdd(&dsum[v], redd[0] + redd[1] + redd[2] + redd[3]);
    }
    __syncthreads();  // vt reused next view
  }
}

// ---------------- scalar chain: softmax + sigmoid gates ---------------------
__global__ void scalar_kernel(const float* __restrict__ logits,
                              const float* __restrict__ dsum,
                              const float* __restrict__ bm, float* __restrict__ gc) {
  if (threadIdx.x == 0 && blockIdx.x == 0) {
    const float scale = 1.0f / sqrtf((float)(NF * N_NODES));
    float l0 = logits[0] * scale, l1 = logits[1] * scale, l2 = logits[2] * scale;
    float mx = fmaxf(l0, fmaxf(l1, l2));
    float e0 = __expf(l0 - mx), e1 = __expf(l1 - mx), e2 = __expf(l2 - mx);
    float inv = 1.0f / (e0 + e1 + e2);
    float g0 = 0.8f * e0 * inv + 0.2f;
    float g1 = 0.8f * e1 * inv + 0.2f;
    float g2 = 0.8f * e2 * inv + 0.2f;
    float bmv = bm[0];
    float o0 = 1.0f / (1.0f + __expf(-(g0 * dsum[0] + bmv)));
    float o1 = 1.0f / (1.0f + __expf(-(g1 * dsum[1] + bmv)));
    float o2 = 1.0f / (1.0f + __expf(-(g2 * dsum[2] + bmv)));
    gc[0] = g0; gc[1] = g1; gc[2] = g2;
    gc[3] = o0 * g0; gc[4] = o1 * g1; gc[5] = o2 * g2;
  }
}

// ---------------- epilogue: mv + result -------------------------------------
__global__ __launch_bounds__(256) void final_kernel(
    const float* __restrict__ views, const float* __restrict__ gc,
    float* __restrict__ out) {
  const size_t NT = (size_t)N_NODES * OUTD;
  size_t base = ((size_t)blockIdx.x * 256 + threadIdx.x) * 4;
  if (base >= NT) return;
  float g0 = gc[0], g1 = gc[1], g2 = gc[2], c0 = gc[3], c1 = gc[4], c2 = gc[5];
  float4 a0 = *(const float4*)(views + base);
  float4 a1 = *(const float4*)(views + NT + base);
  float4 a2 = *(const float4*)(views + 2 * NT + base);
  float4 mv;
  mv.x = c0 * a0.x + c1 * a1.x + c2 * a2.x;
  mv.y = c0 * a0.y + c1 * a1.y + c2 * a2.y;
  mv.z = c0 * a0.z + c1 * a1.z + c2 * a2.z;
  mv.w = c0 * a0.w + c1 * a1.w + c2 * a2.w;
  *(float4*)(out + base) = mv;
  float4 r;
  r.x = 0.5f * (g0 * a0.x) + 0.5f * mv.x;
  r.y = 0.5f * (g0 * a0.y) + 0.5f * mv.y;
  r.z = 0.5f * (g0 * a0.z) + 0.5f * mv.z;
  r.w = 0.5f * (g0 * a0.w) + 0.5f * mv.w;
  *(float4*)(out + NT + base) = r;
  r.x = 0.5f * (g1 * a1.x) + 0.5f * mv.x;
  r.y = 0.5f * (g1 * a1.y) + 0.5f * mv.y;
  r.z = 0.5f * (g1 * a1.z) + 0.5f * mv.z;
  r.w = 0.5f * (g1 * a1.w) + 0.5f * mv.w;
  *(float4*)(out + 2 * NT + base) = r;
  r.x = 0.5f * (g2 * a2.x) + 0.5f * mv.x;
  r.y = 0.5f * (g2 * a2.y) + 0.5f * mv.y;
  r.z = 0.5f * (g2 * a2.z) + 0.5f * mv.z;
  r.w = 0.5f * (g2 * a2.w) + 0.5f * mv.w;
  *(float4*)(out + 3 * NT + base) = r;
}

extern "C" void kernel_launch(void* const* d_in, const int* in_sizes, int n_in,
                              void* d_out, int out_size, void* d_ws, size_t ws_size,
                              hipStream_t stream) {
  const float* x = (const float*)d_in[0];
  const int* src_s = (const int*)d_in[1];
  const int* dst_s = (const int*)d_in[2];
  const int* src_t = (const int*)d_in[3];
  const int* dst_t = (const int*)d_in[4];
  const int* src_p = (const int*)d_in[5];
  const int* dst_p = (const int*)d_in[6];
  const float* W_s = (const float*)d_in[7];
  const float* al_s = (const float*)d_in[8];
  const float* ar_s = (const float*)d_in[9];
  const float* b_s = (const float*)d_in[10];
  const float* W_t = (const float*)d_in[11];
  const float* al_t = (const float*)d_in[12];
  const float* ar_t = (const float*)d_in[13];
  const float* b_t = (const float*)d_in[14];
  const float* W_p = (const float*)d_in[15];
  const float* al_p = (const float*)d_in[16];
  const float* ar_p = (const float*)d_in[17];
  const float* b_p = (const float*)d_in[18];
  const float* Wq = (const float*)d_in[19];
  const float* bq = (const float*)d_in[20];
  const float* Wk = (const float*)d_in[21];
  const float* bk = (const float*)d_in[22];
  const float* Wm = (const float*)d_in[23];
  const float* bm = (const float*)d_in[24];
  float* out = (float*)d_out;

  char* ws = (char*)d_ws;
  unsigned short* feat = (unsigned short*)ws;
  float* el = (float*)(ws + 38400000);
  float* er = (float*)(ws + 43200000);
  float* views = (float*)(ws + 48000000);
  int* offs = (int*)(ws + 124800000);
  int* esrc = (int*)(ws + 126000016);
  int* gtail = (int*)(ws + 136800016);     // 3*64 ints = 768 B
  float* scal = (float*)(ws + 136800784);  // logits[3], dsum[3], gc[6]

  // overlay inside the (not yet written) views buffer
  unsigned int* gbin = (unsigned int*)(ws + 49000000);  // 15,728,640 B

  hipMemsetAsync(gtail, 0, 768 + 48, stream);

  gemm_feat_kernel<<<dim3(391), dim3(256), 0, stream>>>(x, W_s, W_t, W_p, feat);
  elr_kernel<<<dim3((3 * N_NODES * NH + 255) / 256), dim3(256), 0, stream>>>(
      feat, al_s, ar_s, al_t, ar_t, al_p, ar_p, el, er);
  bin_kernel<<<dim3((NE + BIN_EPB - 1) / BIN_EPB, 3), dim3(256), 0, stream>>>(
      src_s, dst_s, src_t, dst_t, src_p, dst_p, gtail, gbin);
  bucket_sort_kernel<<<dim3(NBUCK, 3), dim3(1024), 0, stream>>>(
      gtail, gbin, offs, esrc);
  gat_kernel<<<dim3(12500, 3), dim3(256), 0, stream>>>(
      offs, esrc, el, er, feat, b_s, b_t, b_p, views);
  viewred_kernel<<<dim3(391), dim3(256), 0, stream>>>(
      views, Wq, bq, Wk, bk, Wm, scal, scal + 3);
  scalar_kernel<<<dim3(1), dim3(64), 0, stream>>>(scal, scal + 3, bm, scal + 6);
  final_kernel<<<dim3(6250), dim3(256), 0, stream>>>(views, scal + 6, out);
}